// Round 13
// baseline (382.372 us; speedup 1.0000x reference)
//
#include <hip/hip_runtime.h>
#include <hip/hip_bf16.h>
#include <hip/hip_fp16.h>
#include <math.h>

#define B_ 4
#define T_ 1024
#define D_ 1024
#define H_ 16
#define DH_ 64
#define F_ 4096
#define BT_ (B_ * T_)
#define BTD ((size_t)B_ * T_ * D_)

typedef short bf16x8 __attribute__((ext_vector_type(8)));
typedef _Float16 f16x8 __attribute__((ext_vector_type(8)));
typedef float f32x4 __attribute__((ext_vector_type(4)));

__device__ __forceinline__ unsigned short f2b(float f) {
  __hip_bfloat16 h = __float2bfloat16(f);
  return *reinterpret_cast<unsigned short*>(&h);
}
__device__ __forceinline__ unsigned short f2h(float f) {
  __half h = __float2half(f);
  return *reinterpret_cast<unsigned short*>(&h);
}

__device__ __forceinline__ void gload16(const unsigned short* g, unsigned short* l) {
  __builtin_amdgcn_global_load_lds(
      (const __attribute__((address_space(1))) unsigned int*)(const void*)g,
      (__attribute__((address_space(3))) unsigned int*)(void*)l, 16, 0, 0);
}

// tanh-approx GELU via sigmoid identity: 0.5*(1+tanh(z)) = sigmoid(2z).
__device__ __forceinline__ float gelu_f(float x) {
  float z2 = 1.5957691216057308f * (x + 0.044715f * x * x * x);
  return x / (1.0f + __expf(-z2));
}

// ---------------- block reductions (256 threads, wave64) ----------------
__device__ __forceinline__ float blk_sum256(float v, float* s4) {
#pragma unroll
  for (int off = 32; off > 0; off >>= 1) v += __shfl_down(v, off);
  if ((threadIdx.x & 63) == 0) s4[threadIdx.x >> 6] = v;
  __syncthreads();
  float t = s4[0] + s4[1] + s4[2] + s4[3];
  __syncthreads();
  return t;
}

// ---------------- LayerNorm rows of D=1024, fp32 out + optional bf16 out ----
__global__ __launch_bounds__(256) void ln_rows(
    const float* __restrict__ in, const float* __restrict__ in2,
    const float* __restrict__ g, const float* __restrict__ bb,
    float* __restrict__ outf, unsigned short* __restrict__ outb) {
  __shared__ float s4[4];
  const size_t base = (size_t)blockIdx.x * D_;
  const int t = threadIdx.x;
  float4 v = ((const float4*)(in + base))[t];
  if (in2) {
    float4 w = ((const float4*)(in2 + base))[t];
    v.x += w.x; v.y += w.y; v.z += w.z; v.w += w.w;
  }
  float mean = blk_sum256(v.x + v.y + v.z + v.w, s4) * (1.0f / D_);
  float dx = v.x - mean, dy = v.y - mean, dz = v.z - mean, dw = v.w - mean;
  float var = blk_sum256(dx * dx + dy * dy + dz * dz + dw * dw, s4) * (1.0f / D_);
  float rstd = rsqrtf(var + 1e-5f);
  float4 gv = ((const float4*)g)[t];
  float4 bv = ((const float4*)bb)[t];
  float4 o;
  o.x = dx * rstd * gv.x + bv.x;
  o.y = dy * rstd * gv.y + bv.y;
  o.z = dz * rstd * gv.z + bv.z;
  o.w = dw * rstd * gv.w + bv.w;
  if (outf) ((float4*)(outf + base))[t] = o;
  if (outb) {
    unsigned short o4[4] = {f2b(o.x), f2b(o.y), f2b(o.z), f2b(o.w)};
    *(uint2*)(&outb[base + (size_t)t * 4]) = *(uint2*)o4;
  }
}

// ---------------- transpose+cast fp32 [R][C] -> bf16 [C][R] ----------------
__global__ __launch_bounds__(256) void tcast_t(
    const float* __restrict__ in, unsigned short* __restrict__ out, int R, int C) {
  __shared__ unsigned short tile[32][33];
  const int c0 = blockIdx.x * 32, r0 = blockIdx.y * 32;
  const int col = threadIdx.x & 31, rq = threadIdx.x >> 5;
#pragma unroll
  for (int i = 0; i < 4; ++i) {
    int r = rq + i * 8;
    tile[r][col] = f2b(in[(size_t)(r0 + r) * C + c0 + col]);
  }
  __syncthreads();
#pragma unroll
  for (int i = 0; i < 4; ++i) {
    int r = rq + i * 8;
    out[(size_t)(c0 + r) * R + r0 + col] = tile[col][r];
  }
}

// four 1024x1024 weights at once (z selects)
__global__ __launch_bounds__(256) void tcast4(
    const float* w0, const float* w1, const float* w2, const float* w3,
    unsigned short* o0, unsigned short* o1, unsigned short* o2, unsigned short* o3) {
  __shared__ unsigned short tile[32][33];
  const float* in = blockIdx.z == 0 ? w0 : blockIdx.z == 1 ? w1 : blockIdx.z == 2 ? w2 : w3;
  unsigned short* out = blockIdx.z == 0 ? o0 : blockIdx.z == 1 ? o1 : blockIdx.z == 2 ? o2 : o3;
  const int c0 = blockIdx.x * 32, r0 = blockIdx.y * 32;
  const int col = threadIdx.x & 31, rq = threadIdx.x >> 5;
#pragma unroll
  for (int i = 0; i < 4; ++i) {
    int r = rq + i * 8;
    tile[r][col] = f2b(in[(size_t)(r0 + r) * D_ + c0 + col]);
  }
  __syncthreads();
#pragma unroll
  for (int i = 0; i < 4; ++i) {
    int r = rq + i * 8;
    out[(size_t)(c0 + r) * D_ + r0 + col] = tile[col][r];
  }
}

// ---------------- fused attention: scores + softmax + ctx -------------------
// grid (64, 16): x = bh (XCD = bh%8 -> K/V L2-resident), y = t-tile (64 rows).
__global__ __launch_bounds__(256, 4) void attn_fused(
    const unsigned short* __restrict__ qh, const unsigned short* __restrict__ kh,
    const unsigned short* __restrict__ vt, float* __restrict__ attn,
    unsigned short* __restrict__ ctxb) {
  __shared__ __align__(16) unsigned short Qs[64 * 64];
  __shared__ __align__(16) unsigned short Ks[64 * 64];
  __shared__ __align__(16) unsigned short Vs[64 * 64];
  __shared__ __align__(16) unsigned short Ps[64 * 64];
  const int tid = threadIdx.x;
  const int l = tid & 63, w = tid >> 6;
  const int wm = w >> 1, wn = w & 1;
  const int lk = l >> 4, lr = l & 15;
  const int bh = blockIdx.x, b = bh >> 4, h = bh & 15;
  const int tt = blockIdx.y;
  const unsigned short* Qg = qh + (size_t)b * T_ * D_ + h * DH_ + (size_t)tt * 64 * D_;
  const unsigned short* Kg = kh + (size_t)b * T_ * D_ + h * DH_;
  const unsigned short* Vg = vt + (size_t)bh * 64 * T_;

  const int ar = tid >> 3, ac = tid & 7;
  const int aswz = ((ac ^ (ar & 7)) << 3);

#pragma unroll
  for (int i = 0; i < 2; ++i)
    gload16(Qg + (size_t)(ar + 32 * i) * D_ + aswz, &Qs[(size_t)(i * 256 + tid) * 8]);
  __syncthreads();
  f16x8 qf[2][2];
#pragma unroll
  for (int mi = 0; mi < 2; ++mi) {
    const int row = wm * 32 + mi * 16 + lr;
#pragma unroll
    for (int kk = 0; kk < 2; ++kk)
      qf[mi][kk] = *(const f16x8*)&Qs[row * 64 + (((kk * 4 + lk) ^ (row & 7)) << 3)];
  }

  float lsum[2][4] = {};

  // ---- phase A: row sums ----
  for (int st = 0; st < 16; ++st) {
    __syncthreads();
#pragma unroll
    for (int i = 0; i < 2; ++i)
      gload16(Kg + (size_t)(st * 64 + ar + 32 * i) * D_ + aswz, &Ks[(size_t)(i * 256 + tid) * 8]);
    __syncthreads();
    f16x8 kf[2][2];
#pragma unroll
    for (int ni = 0; ni < 2; ++ni) {
      const int row = wn * 32 + ni * 16 + lr;
#pragma unroll
      for (int kk = 0; kk < 2; ++kk)
        kf[ni][kk] = *(const f16x8*)&Ks[row * 64 + (((kk * 4 + lk) ^ (row & 7)) << 3)];
    }
    f32x4 acc[2][2] = {};
#pragma unroll
    for (int kk = 0; kk < 2; ++kk)
#pragma unroll
      for (int mi = 0; mi < 2; ++mi)
#pragma unroll
        for (int ni = 0; ni < 2; ++ni)
          acc[mi][ni] = __builtin_amdgcn_mfma_f32_16x16x32_f16(
              qf[mi][kk], kf[ni][kk], acc[mi][ni], 0, 0, 0);
#pragma unroll
    for (int mi = 0; mi < 2; ++mi)
#pragma unroll
      for (int r = 0; r < 4; ++r) {
        float v = __expf(acc[mi][0][r] * 0.125f) + __expf(acc[mi][1][r] * 0.125f);
        v += __shfl_xor(v, 1); v += __shfl_xor(v, 2);
        v += __shfl_xor(v, 4); v += __shfl_xor(v, 8);
        lsum[mi][r] += v;
      }
  }

  float* sL = (float*)Ps;
  if (lr == 0) {
#pragma unroll
    for (int mi = 0; mi < 2; ++mi)
#pragma unroll
      for (int r = 0; r < 4; ++r)
        sL[wn * 64 + wm * 32 + mi * 16 + lk * 4 + r] = lsum[mi][r];
  }
  __syncthreads();
  float rl[2][4];
#pragma unroll
  for (int mi = 0; mi < 2; ++mi)
#pragma unroll
    for (int r = 0; r < 4; ++r) {
      const int row = wm * 32 + mi * 16 + lk * 4 + r;
      rl[mi][r] = 1.0f / (sL[row] + sL[64 + row]);
    }
  __syncthreads();

  // ---- phase B: recompute, normalize, write attn, PV ----
  float* Cg = attn + (size_t)bh * T_ * T_;
  f32x4 cacc[2][2] = {};
  for (int st = 0; st < 16; ++st) {
    __syncthreads();
#pragma unroll
    for (int i = 0; i < 2; ++i) {
      gload16(Kg + (size_t)(st * 64 + ar + 32 * i) * D_ + aswz, &Ks[(size_t)(i * 256 + tid) * 8]);
      gload16(Vg + (size_t)(ar + 32 * i) * T_ + st * 64 + aswz, &Vs[(size_t)(i * 256 + tid) * 8]);
    }
    __syncthreads();
    f16x8 kf[2][2], vf[2][2];
#pragma unroll
    for (int ni = 0; ni < 2; ++ni) {
      const int row = wn * 32 + ni * 16 + lr;
#pragma unroll
      for (int kk = 0; kk < 2; ++kk) {
        kf[ni][kk] = *(const f16x8*)&Ks[row * 64 + (((kk * 4 + lk) ^ (row & 7)) << 3)];
        vf[ni][kk] = *(const f16x8*)&Vs[row * 64 + (((kk * 4 + lk) ^ (row & 7)) << 3)];
      }
    }
    f32x4 acc[2][2] = {};
#pragma unroll
    for (int kk = 0; kk < 2; ++kk)
#pragma unroll
      for (int mi = 0; mi < 2; ++mi)
#pragma unroll
        for (int ni = 0; ni < 2; ++ni)
          acc[mi][ni] = __builtin_amdgcn_mfma_f32_16x16x32_f16(
              qf[mi][kk], kf[ni][kk], acc[mi][ni], 0, 0, 0);
#pragma unroll
    for (int mi = 0; mi < 2; ++mi) {
      const int trow = wm * 32 + mi * 16 + lk * 4;
#pragma unroll
      for (int ni = 0; ni < 2; ++ni) {
        const int scol = wn * 32 + ni * 16 + lr;
#pragma unroll
        for (int r = 0; r < 4; ++r) {
          const int t = trow + r;
          float p = __expf(acc[mi][ni][r] * 0.125f) * rl[mi][r];
          __builtin_nontemporal_store(
              p, &Cg[(size_t)(tt * 64 + t) * T_ + (st * 64 + scol)]);
          Ps[t * 64 + (scol ^ ((t & 7) << 3))] = f2h(p);
        }
      }
    }
    __syncthreads();
#pragma unroll
    for (int kk = 0; kk < 2; ++kk) {
      f16x8 af[2];
#pragma unroll
      for (int mi = 0; mi < 2; ++mi) {
        const int row = wm * 32 + mi * 16 + lr;
        af[mi] = *(const f16x8*)&Ps[row * 64 + (((kk * 4 + lk) ^ (row & 7)) << 3)];
      }
#pragma unroll
      for (int mi = 0; mi < 2; ++mi)
#pragma unroll
        for (int ni = 0; ni < 2; ++ni)
          cacc[mi][ni] = __builtin_amdgcn_mfma_f32_16x16x32_f16(
              af[mi], vf[ni][kk], cacc[mi][ni], 0, 0, 0);
    }
  }

  unsigned short* Cb = ctxb + (size_t)b * T_ * D_ + h * DH_;
  const int crow0 = tt * 64 + wm * 32 + lk * 4;
  const int ccol0 = wn * 32 + lr;
#pragma unroll
  for (int mi = 0; mi < 2; ++mi)
#pragma unroll
    for (int ni = 0; ni < 2; ++ni)
#pragma unroll
      for (int r = 0; r < 4; ++r)
        Cb[(size_t)(crow0 + mi * 16 + r) * D_ + ccol0 + ni * 16] = f2b(cacc[mi][ni][r]);
}

// ---------------- MFMA NT GEMM: C[M][N] = A[M][K] @ Bn[N][K]^T ----------------
// EPI: 0=bias, 1=bias+gelu, 2=bias+res1, 3=scale only, 4=bias+res1+res2,
//      5=bias + f16 write TRANSPOSED per head: vt[(b*16+h)*64 + j][t]
// DB: double-buffered LDS, one barrier per K-step (for low-occupancy grids).
template <int BN, int EPI, bool WF32, bool W16, bool FP16 = false, bool DB = false>
__global__ __launch_bounds__(256) void gemm_nt(
    const unsigned short* __restrict__ A, int lda,
    const unsigned short* __restrict__ Bm, int ldb,
    float* __restrict__ Cf, unsigned short* __restrict__ Cb, int ldc,
    const float* __restrict__ bias, const float* __restrict__ r1,
    const float* __restrict__ r2, float scale, int K) {
  constexpr int BM = 128, BK = 64;
  constexpr int WN = BN / 2;
  constexpr int FN = WN / 16;
  constexpr int NB = DB ? 2 : 1;
  __shared__ __align__(16) unsigned short As[NB][BM * BK];
  __shared__ __align__(16) unsigned short Bs[NB][BN * BK];
  const int tid = threadIdx.x;
  const int l = tid & 63;
  const int w = tid >> 6;
  const int wm = w >> 1, wn = w & 1;
  const int lr = l & 15, lk = l >> 4;
  const unsigned short* Ab = A + (size_t)blockIdx.y * BM * lda;
  const unsigned short* Bb = Bm + (size_t)blockIdx.x * BN * ldb;

  const int ar = tid >> 3;
  const int ac = tid & 7;
  const int aswz = ((ac ^ (ar & 7)) << 3);

  f32x4 acc[4][FN] = {};

  auto stage = [&](int buf, int k0) {
#pragma unroll
    for (int i = 0; i < 4; ++i)
      gload16(Ab + (size_t)(ar + 32 * i) * lda + k0 + aswz, &As[buf][(size_t)(i * 256 + tid) * 8]);
#pragma unroll
    for (int i = 0; i < BN / 32; ++i)
      gload16(Bb + (size_t)(ar + 32 * i) * ldb + k0 + aswz, &Bs[buf][(size_t)(i * 256 + tid) * 8]);
  };
  auto compute = [&](int buf) {
    bf16x8 af[4][2], bfr[FN][2];
#pragma unroll
    for (int mi = 0; mi < 4; ++mi) {
      const int row = wm * 64 + mi * 16 + lr;
#pragma unroll
      for (int kk = 0; kk < 2; ++kk)
        af[mi][kk] = *(const bf16x8*)&As[buf][row * BK + (((kk * 4 + lk) ^ (row & 7)) << 3)];
    }
#pragma unroll
    for (int ni = 0; ni < FN; ++ni) {
      const int row = wn * WN + ni * 16 + lr;
#pragma unroll
      for (int kk = 0; kk < 2; ++kk)
        bfr[ni][kk] = *(const bf16x8*)&Bs[buf][row * BK + (((kk * 4 + lk) ^ (row & 7)) << 3)];
    }
#pragma unroll
    for (int kk = 0; kk < 2; ++kk)
#pragma unroll
      for (int mi = 0; mi < 4; ++mi)
#pragma unroll
        for (int ni = 0; ni < FN; ++ni)
          acc[mi][ni] = __builtin_amdgcn_mfma_f32_16x16x32_bf16(
              af[mi][kk], bfr[ni][kk], acc[mi][ni], 0, 0, 0);
  };

  if constexpr (DB) {
    const int nt = K / BK;
    stage(0, 0);
    int cur = 0;
    for (int t = 0; t < nt; ++t) {
      __syncthreads();
      if (t + 1 < nt) stage(cur ^ 1, (t + 1) * BK);
      compute(cur);
      cur ^= 1;
    }
  } else {
    for (int k0 = 0; k0 < K; k0 += BK) {
      stage(0, k0);
      __syncthreads();
      compute(0);
      __syncthreads();
    }
  }

  const int crow0 = blockIdx.y * BM + wm * 64 + lk * 4;
  const int ccol0 = blockIdx.x * BN + wn * WN + lr;
  if constexpr (EPI == 5) {
#pragma unroll
    for (int mi = 0; mi < 4; ++mi)
#pragma unroll
      for (int ni = 0; ni < FN; ++ni) {
        const int row0 = crow0 + mi * 16;
        const int col = ccol0 + ni * 16;
        unsigned short __attribute__((aligned(8))) p4[4];
#pragma unroll
        for (int r = 0; r < 4; ++r) p4[r] = f2h(acc[mi][ni][r] + bias[col]);
        const int bidx = row0 >> 10, t0 = row0 & 1023;
        const int hh = col >> 6, j = col & 63;
        *(uint2*)&Cb[(((size_t)bidx * 16 + hh) * 64 + j) * T_ + t0] = *(uint2*)p4;
      }
  } else {
#pragma unroll
    for (int mi = 0; mi < 4; ++mi)
#pragma unroll
      for (int ni = 0; ni < FN; ++ni)
#pragma unroll
        for (int r = 0; r < 4; ++r) {
          const int row = crow0 + mi * 16 + r;
          const int col = ccol0 + ni * 16;
          float v = acc[mi][ni][r] * scale;
          if (EPI != 3) v += bias[col];
          if (EPI == 1) v = gelu_f(v);
          const size_t off = (size_t)row * ldc + col;
          if (EPI == 2) v += r1[off];
          if (EPI == 4) v += r1[off] + r2[off];
          if (WF32) Cf[off] = v;
          if (W16) Cb[off] = FP16 ? f2h(v) : f2b(v);
        }
  }
}

// ---------------- fused QKV: one N=3072 GEMM over contiguous WqT|WkT|WvT ----
__global__ __launch_bounds__(256) void gemm_qkv(
    const unsigned short* __restrict__ A, const unsigned short* __restrict__ Wt,
    const float* __restrict__ bq, const float* __restrict__ bk,
    const float* __restrict__ bv, const float* __restrict__ sp,
    const float* __restrict__ ed, unsigned short* __restrict__ q_h,
    unsigned short* __restrict__ kb_h, unsigned short* __restrict__ vt) {
  constexpr int BM = 128, BN = 128, BK = 64, K = 1024;
  __shared__ __align__(16) unsigned short As[BM * BK];
  __shared__ __align__(16) unsigned short Bs[BN * BK];
  const int tid = threadIdx.x;
  const int l = tid & 63, w = tid >> 6;
  const int wm = w >> 1, wn = w & 1;
  const int lr = l & 15, lk = l >> 4;
  const unsigned short* Ab = A + (size_t)blockIdx.y * BM * D_;
  const unsigned short* Bb = Wt + (size_t)blockIdx.x * BN * D_;
  const int ar = tid >> 3, ac = tid & 7;
  const int aswz = ((ac ^ (ar & 7)) << 3);

  f32x4 acc[4][4] = {};
  for (int k0 = 0; k0 < K; k0 += BK) {
#pragma unroll
    for (int i = 0; i < 4; ++i) {
      gload16(Ab + (size_t)(ar + 32 * i) * D_ + k0 + aswz, &As[(size_t)(i * 256 + tid) * 8]);
      gload16(Bb + (size_t)(ar + 32 * i) * D_ + k0 + aswz, &Bs[(size_t)(i * 256 + tid) * 8]);
    }
    __syncthreads();
    bf16x8 af[4][2], bfr[4][2];
#pragma unroll
    for (int mi = 0; mi < 4; ++mi) {
      const int row = wm * 64 + mi * 16 + lr;
#pragma unroll
      for (int kk = 0; kk < 2; ++kk)
        af[mi][kk] = *(const bf16x8*)&As[row * BK + (((kk * 4 + lk) ^ (row & 7)) << 3)];
    }
#pragma unroll
    for (int ni = 0; ni < 4; ++ni) {
      const int row = wn * 64 + ni * 16 + lr;
#pragma unroll
      for (int kk = 0; kk < 2; ++kk)
        bfr[ni][kk] = *(const bf16x8*)&Bs[row * BK + (((kk * 4 + lk) ^ (row & 7)) << 3)];
    }
#pragma unroll
    for (int kk = 0; kk < 2; ++kk)
#pragma unroll
      for (int mi = 0; mi < 4; ++mi)
#pragma unroll
        for (int ni = 0; ni < 4; ++ni)
          acc[mi][ni] = __builtin_amdgcn_mfma_f32_16x16x32_bf16(
              af[mi][kk], bfr[ni][kk], acc[mi][ni], 0, 0, 0);
    __syncthreads();
  }

  const int seg = blockIdx.x >> 3;  // 0=Q, 1=K, 2=V
  const float* bias = seg == 0 ? bq : seg == 1 ? bk : bv;
  const int crow0 = blockIdx.y * BM + wm * 64 + lk * 4;
  const int ccol0 = blockIdx.x * BN + wn * 64 + lr;
  if (seg == 2) {
#pragma unroll
    for (int mi = 0; mi < 4; ++mi)
#pragma unroll
      for (int ni = 0; ni < 4; ++ni) {
        const int row0 = crow0 + mi * 16;
        const int col = (ccol0 + ni * 16) & 1023;
        unsigned short __attribute__((aligned(8))) p4[4];
#pragma unroll
        for (int r = 0; r < 4; ++r) p4[r] = f2h(acc[mi][ni][r] + bias[col]);
        const int bidx = row0 >> 10, t0 = row0 & 1023;
        const int hh = col >> 6, j = col & 63;
        *(uint2*)&vt[(((size_t)bidx * 16 + hh) * 64 + j) * T_ + t0] = *(uint2*)p4;
      }
  } else {
    unsigned short* out = seg == 0 ? q_h : kb_h;
#pragma unroll
    for (int mi = 0; mi < 4; ++mi)
#pragma unroll
      for (int ni = 0; ni < 4; ++ni)
#pragma unroll
        for (int r = 0; r < 4; ++r) {
          const int row = crow0 + mi * 16 + r;
          const int col = (ccol0 + ni * 16) & 1023;
          float v = acc[mi][ni][r] + bias[col];
          const size_t off = (size_t)row * D_ + col;
          if (seg == 1) v += sp[off] + ed[off];
          out[off] = f2h(v);
        }
  }
}

extern "C" void kernel_launch(void* const* d_in, const int* in_sizes, int n_in,
                              void* d_out, int out_size, void* d_ws, size_t ws_size,
                              hipStream_t stream) {
  const float* x    = (const float*)d_in[0];
  const float* sp   = (const float*)d_in[1];
  const float* ed   = (const float*)d_in[2];
  const float* ln1g = (const float*)d_in[3];
  const float* ln1b = (const float*)d_in[4];
  const float* Wq   = (const float*)d_in[5];
  const float* bq   = (const float*)d_in[6];
  const float* Wk   = (const float*)d_in[7];
  const float* bk   = (const float*)d_in[8];
  const float* Wv   = (const float*)d_in[9];
  const float* bvv  = (const float*)d_in[10];
  const float* Wo   = (const float*)d_in[11];
  const float* bo   = (const float*)d_in[12];
  const float* ln2g = (const float*)d_in[13];
  const float* ln2b = (const float*)d_in[14];
  const float* W1   = (const float*)d_in[15];
  const float* b1   = (const float*)d_in[16];
  const float* W2   = (const float*)d_in[17];
  const float* b2   = (const float*)d_in[18];
  const float* lnbg = (const float*)d_in[19];
  const float* lnbb = (const float*)d_in[20];

  float* out_x = (float*)d_out;
  float* attn  = out_x + BTD;
  float* tt    = out_x;   // split-K half A of Wo (+bias+residual)

  const size_t MB = 1 << 20;
  char* wsb = (char*)d_ws;
  float*          xn    = (float*)(wsb);                    // [0,16)
  unsigned short* xn_b  = (unsigned short*)(wsb + 16 * MB); // [16,24)
  unsigned short* WqT   = (unsigned short*)(wsb + 24 * MB); // [24,30) Wq|Wk|Wv
  unsigned short* WkT   = (unsigned short*)(wsb + 26 * MB);
  unsigned short* WvT   = (unsigned short*)(wsb + 28 * MB);
  unsigned short* WoT   = (unsigned short*)(wsb + 30 * MB);
  unsigned short* W1T   = (unsigned short*)(wsb + 32 * MB); // [32,40)
  unsigned short* W2T   = (unsigned short*)(wsb + 40 * MB); // [40,48)
  unsigned short* q_h   = (unsigned short*)(wsb + 48 * MB); // [48,56)
  unsigned short* kb_h  = (unsigned short*)(wsb + 56 * MB); // [56,64)
  unsigned short* vt    = (unsigned short*)(wsb + 80 * MB); // [80,88)
  unsigned short* ctx_b = xn_b;                             // [16,24)
  unsigned short* h1_b  = (unsigned short*)(wsb + 48 * MB); // [48,80)
  float*          h2    = (float*)(wsb + 80 * MB);          // [80,96)
  float*          ext   = (float*)(wsb + 96 * MB);          // [96,112): tt_b, then h2b
  float*          y     = xn;
  unsigned short* y_b   = xn_b;
  float*          tt_b  = ext;   // Wo split-K half B (raw partial)
  float*          h2b   = ext;   // FFN2 split-K half B (disjoint lifetime)

  dim3 blk(256);
  dim3 g_dd(8, 32);

  // 1. LN1 -> xn (fp32 residual) + xn_b (bf16 GEMM operand)
  ln_rows<<<BT_, blk, 0, stream>>>(x, nullptr, ln1g, ln1b, xn, xn_b);
  // 2. weight transpose+cast
  tcast4<<<dim3(32, 32, 4), blk, 0, stream>>>(Wq, Wk, Wv, Wo, WqT, WkT, WvT, WoT);
  tcast_t<<<dim3(128, 32), blk, 0, stream>>>(W1, W1T, 1024, 4096);
  tcast_t<<<dim3(32, 128), blk, 0, stream>>>(W2, W2T, 4096, 1024);
  // 3. fused QKV (768 blocks): Q->f16, K(+sp+ed)->f16, V->f16 transposed
  gemm_qkv<<<dim3(24, 32), blk, 0, stream>>>(
      xn_b, WqT, bq, bk, bvv, sp, ed, q_h, kb_h, vt);
  // 4. fused scores + softmax + ctx (1024 blocks, 4/CU)
  attn_fused<<<dim3(64, 16), blk, 0, stream>>>(q_h, kb_h, vt, attn, ctx_b);
  // 5. Wo split-K x2 (512 blocks total): tt = ctx@Wo[:,0:512] + bo + xn;
  //    tt_b = ctx@Wo[:,512:1024]
  gemm_nt<128, 2, true, false, false, true><<<g_dd, blk, 0, stream>>>(
      ctx_b, D_, WoT, D_, tt, nullptr, D_, bo, xn, nullptr, 1.f, 512);
  gemm_nt<128, 3, true, false, false, true><<<g_dd, blk, 0, stream>>>(
      ctx_b + 512, D_, WoT + 512, D_, tt_b, nullptr, D_, nullptr, nullptr, nullptr, 1.f, 512);
  // 6. y = LN2(tt + tt_b)
  ln_rows<<<BT_, blk, 0, stream>>>(tt, tt_b, ln2g, ln2b, y, y_b);
  // 7. h1 = gelu(y @ W1 + b1) -> bf16 (MFMA, 1024 blocks)
  gemm_nt<128, 1, false, true><<<dim3(32, 32), blk, 0, stream>>>(
      y_b, D_, W1T, D_, nullptr, h1_b, F_, b1, nullptr, nullptr, 1.f, D_);
  // 8. FFN2 split-K x2 (512 blocks total):
  //    h2 = y + h1[:,0:2048]@W2[0:2048] + b2;  h2b = h1[:,2048:]@W2[2048:]
  gemm_nt<128, 2, true, false, false, true><<<g_dd, blk, 0, stream>>>(
      h1_b, F_, W2T, F_, h2, nullptr, D_, b2, y, nullptr, 1.f, 2048);
  gemm_nt<128, 3, true, false, false, true><<<g_dd, blk, 0, stream>>>(
      h1_b + 2048, F_, W2T + 2048, F_, h2b, nullptr, D_, nullptr, nullptr, nullptr, 1.f, 2048);
  // 9. out = LN(h2 + h2b)
  ln_rows<<<BT_, blk, 0, stream>>>(h2, h2b, lnbg, lnbb, out_x, nullptr);
}

// Round 14
// 367.086 us; speedup vs baseline: 1.0416x; 1.0416x over previous
//
#include <hip/hip_runtime.h>
#include <hip/hip_bf16.h>
#include <hip/hip_fp16.h>
#include <math.h>

#define B_ 4
#define T_ 1024
#define D_ 1024
#define H_ 16
#define DH_ 64
#define F_ 4096
#define BT_ (B_ * T_)
#define BTD ((size_t)B_ * T_ * D_)

typedef short bf16x8 __attribute__((ext_vector_type(8)));
typedef _Float16 f16x8 __attribute__((ext_vector_type(8)));
typedef float f32x4 __attribute__((ext_vector_type(4)));

__device__ __forceinline__ unsigned short f2b(float f) {
  __hip_bfloat16 h = __float2bfloat16(f);
  return *reinterpret_cast<unsigned short*>(&h);
}
__device__ __forceinline__ unsigned short f2h(float f) {
  __half h = __float2half(f);
  return *reinterpret_cast<unsigned short*>(&h);
}

__device__ __forceinline__ void gload16(const unsigned short* g, unsigned short* l) {
  __builtin_amdgcn_global_load_lds(
      (const __attribute__((address_space(1))) unsigned int*)(const void*)g,
      (__attribute__((address_space(3))) unsigned int*)(void*)l, 16, 0, 0);
}

// tanh-approx GELU via sigmoid identity: 0.5*(1+tanh(z)) = sigmoid(2z).
__device__ __forceinline__ float gelu_f(float x) {
  float z2 = 1.5957691216057308f * (x + 0.044715f * x * x * x);
  return x / (1.0f + __expf(-z2));
}

// ---------------- block reductions (256 threads, wave64) ----------------
__device__ __forceinline__ float blk_sum256(float v, float* s4) {
#pragma unroll
  for (int off = 32; off > 0; off >>= 1) v += __shfl_down(v, off);
  if ((threadIdx.x & 63) == 0) s4[threadIdx.x >> 6] = v;
  __syncthreads();
  float t = s4[0] + s4[1] + s4[2] + s4[3];
  __syncthreads();
  return t;
}

// ---------------- LayerNorm rows of D=1024, fp32 out + optional bf16 out ----
__global__ __launch_bounds__(256) void ln_rows(
    const float* __restrict__ in, const float* __restrict__ in2,
    const float* __restrict__ g, const float* __restrict__ bb,
    float* __restrict__ outf, unsigned short* __restrict__ outb) {
  __shared__ float s4[4];
  const size_t base = (size_t)blockIdx.x * D_;
  const int t = threadIdx.x;
  float4 v = ((const float4*)(in + base))[t];
  if (in2) {
    float4 w = ((const float4*)(in2 + base))[t];
    v.x += w.x; v.y += w.y; v.z += w.z; v.w += w.w;
  }
  float mean = blk_sum256(v.x + v.y + v.z + v.w, s4) * (1.0f / D_);
  float dx = v.x - mean, dy = v.y - mean, dz = v.z - mean, dw = v.w - mean;
  float var = blk_sum256(dx * dx + dy * dy + dz * dz + dw * dw, s4) * (1.0f / D_);
  float rstd = rsqrtf(var + 1e-5f);
  float4 gv = ((const float4*)g)[t];
  float4 bv = ((const float4*)bb)[t];
  float4 o;
  o.x = dx * rstd * gv.x + bv.x;
  o.y = dy * rstd * gv.y + bv.y;
  o.z = dz * rstd * gv.z + bv.z;
  o.w = dw * rstd * gv.w + bv.w;
  if (outf) ((float4*)(outf + base))[t] = o;
  if (outb) {
    unsigned short o4[4] = {f2b(o.x), f2b(o.y), f2b(o.z), f2b(o.w)};
    *(uint2*)(&outb[base + (size_t)t * 4]) = *(uint2*)o4;
  }
}

// ---------------- transpose+cast fp32 [R][C] -> bf16 [C][R] ----------------
__global__ __launch_bounds__(256) void tcast_t(
    const float* __restrict__ in, unsigned short* __restrict__ out, int R, int C) {
  __shared__ unsigned short tile[32][33];
  const int c0 = blockIdx.x * 32, r0 = blockIdx.y * 32;
  const int col = threadIdx.x & 31, rq = threadIdx.x >> 5;
#pragma unroll
  for (int i = 0; i < 4; ++i) {
    int r = rq + i * 8;
    tile[r][col] = f2b(in[(size_t)(r0 + r) * C + c0 + col]);
  }
  __syncthreads();
#pragma unroll
  for (int i = 0; i < 4; ++i) {
    int r = rq + i * 8;
    out[(size_t)(c0 + r) * R + r0 + col] = tile[col][r];
  }
}

// four 1024x1024 weights at once (z selects)
__global__ __launch_bounds__(256) void tcast4(
    const float* w0, const float* w1, const float* w2, const float* w3,
    unsigned short* o0, unsigned short* o1, unsigned short* o2, unsigned short* o3) {
  __shared__ unsigned short tile[32][33];
  const float* in = blockIdx.z == 0 ? w0 : blockIdx.z == 1 ? w1 : blockIdx.z == 2 ? w2 : w3;
  unsigned short* out = blockIdx.z == 0 ? o0 : blockIdx.z == 1 ? o1 : blockIdx.z == 2 ? o2 : o3;
  const int c0 = blockIdx.x * 32, r0 = blockIdx.y * 32;
  const int col = threadIdx.x & 31, rq = threadIdx.x >> 5;
#pragma unroll
  for (int i = 0; i < 4; ++i) {
    int r = rq + i * 8;
    tile[r][col] = f2b(in[(size_t)(r0 + r) * D_ + c0 + col]);
  }
  __syncthreads();
#pragma unroll
  for (int i = 0; i < 4; ++i) {
    int r = rq + i * 8;
    out[(size_t)(c0 + r) * D_ + r0 + col] = tile[col][r];
  }
}

// ---------------- fused attention: scores + softmax + ctx -------------------
// grid (64, 16): x = bh (XCD = bh%8 -> K/V L2-resident), y = t-tile (64 rows).
__global__ __launch_bounds__(256, 4) void attn_fused(
    const unsigned short* __restrict__ qh, const unsigned short* __restrict__ kh,
    const unsigned short* __restrict__ vt, float* __restrict__ attn,
    unsigned short* __restrict__ ctxb) {
  __shared__ __align__(16) unsigned short Qs[64 * 64];
  __shared__ __align__(16) unsigned short Ks[64 * 64];
  __shared__ __align__(16) unsigned short Vs[64 * 64];
  __shared__ __align__(16) unsigned short Ps[64 * 64];
  const int tid = threadIdx.x;
  const int l = tid & 63, w = tid >> 6;
  const int wm = w >> 1, wn = w & 1;
  const int lk = l >> 4, lr = l & 15;
  const int bh = blockIdx.x, b = bh >> 4, h = bh & 15;
  const int tt = blockIdx.y;
  const unsigned short* Qg = qh + (size_t)b * T_ * D_ + h * DH_ + (size_t)tt * 64 * D_;
  const unsigned short* Kg = kh + (size_t)b * T_ * D_ + h * DH_;
  const unsigned short* Vg = vt + (size_t)bh * 64 * T_;

  const int ar = tid >> 3, ac = tid & 7;
  const int aswz = ((ac ^ (ar & 7)) << 3);

#pragma unroll
  for (int i = 0; i < 2; ++i)
    gload16(Qg + (size_t)(ar + 32 * i) * D_ + aswz, &Qs[(size_t)(i * 256 + tid) * 8]);
  __syncthreads();
  f16x8 qf[2][2];
#pragma unroll
  for (int mi = 0; mi < 2; ++mi) {
    const int row = wm * 32 + mi * 16 + lr;
#pragma unroll
    for (int kk = 0; kk < 2; ++kk)
      qf[mi][kk] = *(const f16x8*)&Qs[row * 64 + (((kk * 4 + lk) ^ (row & 7)) << 3)];
  }

  float lsum[2][4] = {};

  // ---- phase A: row sums ----
  for (int st = 0; st < 16; ++st) {
    __syncthreads();
#pragma unroll
    for (int i = 0; i < 2; ++i)
      gload16(Kg + (size_t)(st * 64 + ar + 32 * i) * D_ + aswz, &Ks[(size_t)(i * 256 + tid) * 8]);
    __syncthreads();
    f16x8 kf[2][2];
#pragma unroll
    for (int ni = 0; ni < 2; ++ni) {
      const int row = wn * 32 + ni * 16 + lr;
#pragma unroll
      for (int kk = 0; kk < 2; ++kk)
        kf[ni][kk] = *(const f16x8*)&Ks[row * 64 + (((kk * 4 + lk) ^ (row & 7)) << 3)];
    }
    f32x4 acc[2][2] = {};
#pragma unroll
    for (int kk = 0; kk < 2; ++kk)
#pragma unroll
      for (int mi = 0; mi < 2; ++mi)
#pragma unroll
        for (int ni = 0; ni < 2; ++ni)
          acc[mi][ni] = __builtin_amdgcn_mfma_f32_16x16x32_f16(
              qf[mi][kk], kf[ni][kk], acc[mi][ni], 0, 0, 0);
#pragma unroll
    for (int mi = 0; mi < 2; ++mi)
#pragma unroll
      for (int r = 0; r < 4; ++r) {
        float v = __expf(acc[mi][0][r] * 0.125f) + __expf(acc[mi][1][r] * 0.125f);
        v += __shfl_xor(v, 1); v += __shfl_xor(v, 2);
        v += __shfl_xor(v, 4); v += __shfl_xor(v, 8);
        lsum[mi][r] += v;
      }
  }

  float* sL = (float*)Ps;
  if (lr == 0) {
#pragma unroll
    for (int mi = 0; mi < 2; ++mi)
#pragma unroll
      for (int r = 0; r < 4; ++r)
        sL[wn * 64 + wm * 32 + mi * 16 + lk * 4 + r] = lsum[mi][r];
  }
  __syncthreads();
  float rl[2][4];
#pragma unroll
  for (int mi = 0; mi < 2; ++mi)
#pragma unroll
    for (int r = 0; r < 4; ++r) {
      const int row = wm * 32 + mi * 16 + lk * 4 + r;
      rl[mi][r] = 1.0f / (sL[row] + sL[64 + row]);
    }
  __syncthreads();

  // ---- phase B: recompute, normalize, write attn, PV ----
  float* Cg = attn + (size_t)bh * T_ * T_;
  f32x4 cacc[2][2] = {};
  for (int st = 0; st < 16; ++st) {
    __syncthreads();
#pragma unroll
    for (int i = 0; i < 2; ++i) {
      gload16(Kg + (size_t)(st * 64 + ar + 32 * i) * D_ + aswz, &Ks[(size_t)(i * 256 + tid) * 8]);
      gload16(Vg + (size_t)(ar + 32 * i) * T_ + st * 64 + aswz, &Vs[(size_t)(i * 256 + tid) * 8]);
    }
    __syncthreads();
    f16x8 kf[2][2], vf[2][2];
#pragma unroll
    for (int ni = 0; ni < 2; ++ni) {
      const int row = wn * 32 + ni * 16 + lr;
#pragma unroll
      for (int kk = 0; kk < 2; ++kk) {
        kf[ni][kk] = *(const f16x8*)&Ks[row * 64 + (((kk * 4 + lk) ^ (row & 7)) << 3)];
        vf[ni][kk] = *(const f16x8*)&Vs[row * 64 + (((kk * 4 + lk) ^ (row & 7)) << 3)];
      }
    }
    f32x4 acc[2][2] = {};
#pragma unroll
    for (int kk = 0; kk < 2; ++kk)
#pragma unroll
      for (int mi = 0; mi < 2; ++mi)
#pragma unroll
        for (int ni = 0; ni < 2; ++ni)
          acc[mi][ni] = __builtin_amdgcn_mfma_f32_16x16x32_f16(
              qf[mi][kk], kf[ni][kk], acc[mi][ni], 0, 0, 0);
#pragma unroll
    for (int mi = 0; mi < 2; ++mi) {
      const int trow = wm * 32 + mi * 16 + lk * 4;
#pragma unroll
      for (int ni = 0; ni < 2; ++ni) {
        const int scol = wn * 32 + ni * 16 + lr;
#pragma unroll
        for (int r = 0; r < 4; ++r) {
          const int t = trow + r;
          float p = __expf(acc[mi][ni][r] * 0.125f) * rl[mi][r];
          __builtin_nontemporal_store(
              p, &Cg[(size_t)(tt * 64 + t) * T_ + (st * 64 + scol)]);
          Ps[t * 64 + (scol ^ ((t & 7) << 3))] = f2h(p);
        }
      }
    }
    __syncthreads();
#pragma unroll
    for (int kk = 0; kk < 2; ++kk) {
      f16x8 af[2];
#pragma unroll
      for (int mi = 0; mi < 2; ++mi) {
        const int row = wm * 32 + mi * 16 + lr;
        af[mi] = *(const f16x8*)&Ps[row * 64 + (((kk * 4 + lk) ^ (row & 7)) << 3)];
      }
#pragma unroll
      for (int mi = 0; mi < 2; ++mi)
#pragma unroll
        for (int ni = 0; ni < 2; ++ni)
          cacc[mi][ni] = __builtin_amdgcn_mfma_f32_16x16x32_f16(
              af[mi], vf[ni][kk], cacc[mi][ni], 0, 0, 0);
    }
  }

  unsigned short* Cb = ctxb + (size_t)b * T_ * D_ + h * DH_;
  const int crow0 = tt * 64 + wm * 32 + lk * 4;
  const int ccol0 = wn * 32 + lr;
#pragma unroll
  for (int mi = 0; mi < 2; ++mi)
#pragma unroll
    for (int ni = 0; ni < 2; ++ni)
#pragma unroll
      for (int r = 0; r < 4; ++r)
        Cb[(size_t)(crow0 + mi * 16 + r) * D_ + ccol0 + ni * 16] = f2b(cacc[mi][ni][r]);
}

// ---------------- MFMA NT GEMM: C[M][N] = A[M][K] @ Bn[N][K]^T ----------------
// EPI: 0=bias, 1=bias+gelu, 2=bias+res1, 3=scale only, 4=bias+res1+res2,
//      5=bias + f16 write TRANSPOSED per head: vt[(b*16+h)*64 + j][t]
// DB: 4-buffer, 3-tiles-in-flight pipeline with counted vmcnt (T3/T4) — for
//     inherently 1-block/CU grids where barrier vmcnt(0) drains expose latency.
template <int BN, int EPI, bool WF32, bool W16, bool FP16 = false, bool DB = false>
__global__ __launch_bounds__(256) void gemm_nt(
    const unsigned short* __restrict__ A, int lda,
    const unsigned short* __restrict__ Bm, int ldb,
    float* __restrict__ Cf, unsigned short* __restrict__ Cb, int ldc,
    const float* __restrict__ bias, const float* __restrict__ r1,
    const float* __restrict__ r2, float scale, int K) {
  constexpr int BM = 128, BK = 64;
  constexpr int WN = BN / 2;
  constexpr int FN = WN / 16;
  constexpr int NB = DB ? 4 : 1;
  static_assert(!DB || BN == 128, "counted vmcnt constants assume 8 loads/stage");
  __shared__ __align__(16) unsigned short As[NB][BM * BK];
  __shared__ __align__(16) unsigned short Bs[NB][BN * BK];
  const int tid = threadIdx.x;
  const int l = tid & 63;
  const int w = tid >> 6;
  const int wm = w >> 1, wn = w & 1;
  const int lr = l & 15, lk = l >> 4;
  const unsigned short* Ab = A + (size_t)blockIdx.y * BM * lda;
  const unsigned short* Bb = Bm + (size_t)blockIdx.x * BN * ldb;

  const int ar = tid >> 3;
  const int ac = tid & 7;
  const int aswz = ((ac ^ (ar & 7)) << 3);

  f32x4 acc[4][FN] = {};

  auto stage = [&](int buf, int k0) {
#pragma unroll
    for (int i = 0; i < 4; ++i)
      gload16(Ab + (size_t)(ar + 32 * i) * lda + k0 + aswz, &As[buf][(size_t)(i * 256 + tid) * 8]);
#pragma unroll
    for (int i = 0; i < BN / 32; ++i)
      gload16(Bb + (size_t)(ar + 32 * i) * ldb + k0 + aswz, &Bs[buf][(size_t)(i * 256 + tid) * 8]);
  };
  auto compute = [&](int buf) {
    bf16x8 af[4][2], bfr[FN][2];
#pragma unroll
    for (int mi = 0; mi < 4; ++mi) {
      const int row = wm * 64 + mi * 16 + lr;
#pragma unroll
      for (int kk = 0; kk < 2; ++kk)
        af[mi][kk] = *(const bf16x8*)&As[buf][row * BK + (((kk * 4 + lk) ^ (row & 7)) << 3)];
    }
#pragma unroll
    for (int ni = 0; ni < FN; ++ni) {
      const int row = wn * WN + ni * 16 + lr;
#pragma unroll
      for (int kk = 0; kk < 2; ++kk)
        bfr[ni][kk] = *(const bf16x8*)&Bs[buf][row * BK + (((kk * 4 + lk) ^ (row & 7)) << 3)];
    }
#pragma unroll
    for (int kk = 0; kk < 2; ++kk)
#pragma unroll
      for (int mi = 0; mi < 4; ++mi)
#pragma unroll
        for (int ni = 0; ni < FN; ++ni)
          acc[mi][ni] = __builtin_amdgcn_mfma_f32_16x16x32_bf16(
              af[mi][kk], bfr[ni][kk], acc[mi][ni], 0, 0, 0);
  };

  if constexpr (DB) {
    const int nt = K / BK;  // >= 4 for all our uses (K >= 256)
    stage(0, 0);
    stage(1, BK);
    stage(2, 2 * BK);
    for (int t = 0; t < nt; ++t) {
      const int rem = nt - 1 - t;  // tiles still to compute after this one
      // per-wave: wait until this tile's 8 loads landed; newer tiles stay in
      // flight. Barrier then makes every wave's tile-t data + buffer-reuse
      // ordering globally valid (all waves passed their own vmcnt + compute).
      if (rem >= 2)      asm volatile("s_waitcnt vmcnt(16)" ::: "memory");
      else if (rem == 1) asm volatile("s_waitcnt vmcnt(8)" ::: "memory");
      else               asm volatile("s_waitcnt vmcnt(0)" ::: "memory");
      __builtin_amdgcn_s_barrier();
      __builtin_amdgcn_sched_barrier(0);
      if (t + 3 < nt) stage((t + 3) & 3, (t + 3) * BK);
      compute(t & 3);
    }
  } else {
    for (int k0 = 0; k0 < K; k0 += BK) {
      stage(0, k0);
      __syncthreads();
      compute(0);
      __syncthreads();
    }
  }

  const int crow0 = blockIdx.y * BM + wm * 64 + lk * 4;
  const int ccol0 = blockIdx.x * BN + wn * WN + lr;
  if constexpr (EPI == 5) {
#pragma unroll
    for (int mi = 0; mi < 4; ++mi)
#pragma unroll
      for (int ni = 0; ni < FN; ++ni) {
        const int row0 = crow0 + mi * 16;
        const int col = ccol0 + ni * 16;
        unsigned short __attribute__((aligned(8))) p4[4];
#pragma unroll
        for (int r = 0; r < 4; ++r) p4[r] = f2h(acc[mi][ni][r] + bias[col]);
        const int bidx = row0 >> 10, t0 = row0 & 1023;
        const int hh = col >> 6, j = col & 63;
        *(uint2*)&Cb[(((size_t)bidx * 16 + hh) * 64 + j) * T_ + t0] = *(uint2*)p4;
      }
  } else {
#pragma unroll
    for (int mi = 0; mi < 4; ++mi)
#pragma unroll
      for (int ni = 0; ni < FN; ++ni)
#pragma unroll
        for (int r = 0; r < 4; ++r) {
          const int row = crow0 + mi * 16 + r;
          const int col = ccol0 + ni * 16;
          float v = acc[mi][ni][r] * scale;
          if (EPI != 3) v += bias[col];
          if (EPI == 1) v = gelu_f(v);
          const size_t off = (size_t)row * ldc + col;
          if (EPI == 2) v += r1[off];
          if (EPI == 4) v += r1[off] + r2[off];
          if (WF32) Cf[off] = v;
          if (W16) Cb[off] = FP16 ? f2h(v) : f2b(v);
        }
  }
}

// ---------------- fused QKV: one N=3072 GEMM over contiguous WqT|WkT|WvT ----
__global__ __launch_bounds__(256) void gemm_qkv(
    const unsigned short* __restrict__ A, const unsigned short* __restrict__ Wt,
    const float* __restrict__ bq, const float* __restrict__ bk,
    const float* __restrict__ bv, const float* __restrict__ sp,
    const float* __restrict__ ed, unsigned short* __restrict__ q_h,
    unsigned short* __restrict__ kb_h, unsigned short* __restrict__ vt) {
  constexpr int BM = 128, BN = 128, BK = 64, K = 1024;
  __shared__ __align__(16) unsigned short As[BM * BK];
  __shared__ __align__(16) unsigned short Bs[BN * BK];
  const int tid = threadIdx.x;
  const int l = tid & 63, w = tid >> 6;
  const int wm = w >> 1, wn = w & 1;
  const int lr = l & 15, lk = l >> 4;
  const unsigned short* Ab = A + (size_t)blockIdx.y * BM * D_;
  const unsigned short* Bb = Wt + (size_t)blockIdx.x * BN * D_;
  const int ar = tid >> 3, ac = tid & 7;
  const int aswz = ((ac ^ (ar & 7)) << 3);

  f32x4 acc[4][4] = {};
  for (int k0 = 0; k0 < K; k0 += BK) {
#pragma unroll
    for (int i = 0; i < 4; ++i) {
      gload16(Ab + (size_t)(ar + 32 * i) * D_ + k0 + aswz, &As[(size_t)(i * 256 + tid) * 8]);
      gload16(Bb + (size_t)(ar + 32 * i) * D_ + k0 + aswz, &Bs[(size_t)(i * 256 + tid) * 8]);
    }
    __syncthreads();
    bf16x8 af[4][2], bfr[4][2];
#pragma unroll
    for (int mi = 0; mi < 4; ++mi) {
      const int row = wm * 64 + mi * 16 + lr;
#pragma unroll
      for (int kk = 0; kk < 2; ++kk)
        af[mi][kk] = *(const bf16x8*)&As[row * BK + (((kk * 4 + lk) ^ (row & 7)) << 3)];
    }
#pragma unroll
    for (int ni = 0; ni < 4; ++ni) {
      const int row = wn * 64 + ni * 16 + lr;
#pragma unroll
      for (int kk = 0; kk < 2; ++kk)
        bfr[ni][kk] = *(const bf16x8*)&Bs[row * BK + (((kk * 4 + lk) ^ (row & 7)) << 3)];
    }
#pragma unroll
    for (int kk = 0; kk < 2; ++kk)
#pragma unroll
      for (int mi = 0; mi < 4; ++mi)
#pragma unroll
        for (int ni = 0; ni < 4; ++ni)
          acc[mi][ni] = __builtin_amdgcn_mfma_f32_16x16x32_bf16(
              af[mi][kk], bfr[ni][kk], acc[mi][ni], 0, 0, 0);
    __syncthreads();
  }

  const int seg = blockIdx.x >> 3;  // 0=Q, 1=K, 2=V
  const float* bias = seg == 0 ? bq : seg == 1 ? bk : bv;
  const int crow0 = blockIdx.y * BM + wm * 64 + lk * 4;
  const int ccol0 = blockIdx.x * BN + wn * 64 + lr;
  if (seg == 2) {
#pragma unroll
    for (int mi = 0; mi < 4; ++mi)
#pragma unroll
      for (int ni = 0; ni < 4; ++ni) {
        const int row0 = crow0 + mi * 16;
        const int col = (ccol0 + ni * 16) & 1023;
        unsigned short __attribute__((aligned(8))) p4[4];
#pragma unroll
        for (int r = 0; r < 4; ++r) p4[r] = f2h(acc[mi][ni][r] + bias[col]);
        const int bidx = row0 >> 10, t0 = row0 & 1023;
        const int hh = col >> 6, j = col & 63;
        *(uint2*)&vt[(((size_t)bidx * 16 + hh) * 64 + j) * T_ + t0] = *(uint2*)p4;
      }
  } else {
    unsigned short* out = seg == 0 ? q_h : kb_h;
#pragma unroll
    for (int mi = 0; mi < 4; ++mi)
#pragma unroll
      for (int ni = 0; ni < 4; ++ni)
#pragma unroll
        for (int r = 0; r < 4; ++r) {
          const int row = crow0 + mi * 16 + r;
          const int col = (ccol0 + ni * 16) & 1023;
          float v = acc[mi][ni][r] + bias[col];
          const size_t off = (size_t)row * D_ + col;
          if (seg == 1) v += sp[off] + ed[off];
          out[off] = f2h(v);
        }
  }
}

extern "C" void kernel_launch(void* const* d_in, const int* in_sizes, int n_in,
                              void* d_out, int out_size, void* d_ws, size_t ws_size,
                              hipStream_t stream) {
  const float* x    = (const float*)d_in[0];
  const float* sp   = (const float*)d_in[1];
  const float* ed   = (const float*)d_in[2];
  const float* ln1g = (const float*)d_in[3];
  const float* ln1b = (const float*)d_in[4];
  const float* Wq   = (const float*)d_in[5];
  const float* bq   = (const float*)d_in[6];
  const float* Wk   = (const float*)d_in[7];
  const float* bk   = (const float*)d_in[8];
  const float* Wv   = (const float*)d_in[9];
  const float* bvv  = (const float*)d_in[10];
  const float* Wo   = (const float*)d_in[11];
  const float* bo   = (const float*)d_in[12];
  const float* ln2g = (const float*)d_in[13];
  const float* ln2b = (const float*)d_in[14];
  const float* W1   = (const float*)d_in[15];
  const float* b1   = (const float*)d_in[16];
  const float* W2   = (const float*)d_in[17];
  const float* b2   = (const float*)d_in[18];
  const float* lnbg = (const float*)d_in[19];
  const float* lnbb = (const float*)d_in[20];

  float* out_x = (float*)d_out;
  float* attn  = out_x + BTD;
  float* tt    = out_x;

  const size_t MB = 1 << 20;
  char* wsb = (char*)d_ws;
  float*          xn    = (float*)(wsb);                    // [0,16)
  unsigned short* xn_b  = (unsigned short*)(wsb + 16 * MB); // [16,24)
  unsigned short* WqT   = (unsigned short*)(wsb + 24 * MB); // [24,30) Wq|Wk|Wv
  unsigned short* WkT   = (unsigned short*)(wsb + 26 * MB);
  unsigned short* WvT   = (unsigned short*)(wsb + 28 * MB);
  unsigned short* WoT   = (unsigned short*)(wsb + 30 * MB);
  unsigned short* W1T   = (unsigned short*)(wsb + 32 * MB); // [32,40)
  unsigned short* W2T   = (unsigned short*)(wsb + 40 * MB); // [40,48)
  unsigned short* q_h   = (unsigned short*)(wsb + 48 * MB); // [48,56)
  unsigned short* kb_h  = (unsigned short*)(wsb + 56 * MB); // [56,64)
  unsigned short* vt    = (unsigned short*)(wsb + 80 * MB); // [80,88)
  unsigned short* ctx_b = xn_b;                             // [16,24)
  unsigned short* h1_b  = (unsigned short*)(wsb + 48 * MB); // [48,80)
  float*          h2    = (float*)(wsb + 80 * MB);          // [80,96)
  float*          y     = xn;
  unsigned short* y_b   = xn_b;

  dim3 blk(256);
  dim3 g_dd(8, 32);

  // 1. LN1 -> xn (fp32 residual) + xn_b (bf16 GEMM operand)
  ln_rows<<<BT_, blk, 0, stream>>>(x, nullptr, ln1g, ln1b, xn, xn_b);
  // 2. weight transpose+cast
  tcast4<<<dim3(32, 32, 4), blk, 0, stream>>>(Wq, Wk, Wv, Wo, WqT, WkT, WvT, WoT);
  tcast_t<<<dim3(128, 32), blk, 0, stream>>>(W1, W1T, 1024, 4096);
  tcast_t<<<dim3(32, 128), blk, 0, stream>>>(W2, W2T, 4096, 1024);
  // 3. fused QKV (768 blocks): Q->f16, K(+sp+ed)->f16, V->f16 transposed
  gemm_qkv<<<dim3(24, 32), blk, 0, stream>>>(
      xn_b, WqT, bq, bk, bvv, sp, ed, q_h, kb_h, vt);
  // 4. fused scores + softmax + ctx (1024 blocks, 4/CU)
  attn_fused<<<dim3(64, 16), blk, 0, stream>>>(q_h, kb_h, vt, attn, ctx_b);
  // 5. tt = ctx @ Wo + bo + xn (MFMA, 4-deep counted-vmcnt pipeline)
  gemm_nt<128, 2, true, false, false, true><<<g_dd, blk, 0, stream>>>(
      ctx_b, D_, WoT, D_, tt, nullptr, D_, bo, xn, nullptr, 1.f, D_);
  // 6. y = LN2(tt)
  ln_rows<<<BT_, blk, 0, stream>>>(tt, nullptr, ln2g, ln2b, y, y_b);
  // 7. h1 = gelu(y @ W1 + b1) -> bf16 (MFMA, 1024 blocks single-buffer)
  gemm_nt<128, 1, false, true><<<dim3(32, 32), blk, 0, stream>>>(
      y_b, D_, W1T, D_, nullptr, h1_b, F_, b1, nullptr, nullptr, 1.f, D_);
  // 8. h2 = y + (h1 @ W2 + b2)  (MFMA, 4-deep counted-vmcnt pipeline)
  gemm_nt<128, 2, true, false, false, true><<<g_dd, blk, 0, stream>>>(
      h1_b, F_, W2T, F_, h2, nullptr, D_, b2, y, nullptr, 1.f, F_);
  // 9. out = LN(h2)
  ln_rows<<<BT_, blk, 0, stream>>>(h2, nullptr, lnbg, lnbb, out_x, nullptr);
}

// Round 15
// 356.517 us; speedup vs baseline: 1.0725x; 1.0296x over previous
//
#include <hip/hip_runtime.h>
#include <hip/hip_bf16.h>
#include <hip/hip_fp16.h>
#include <math.h>

#define B_ 4
#define T_ 1024
#define D_ 1024
#define H_ 16
#define DH_ 64
#define F_ 4096
#define BT_ (B_ * T_)
#define BTD ((size_t)B_ * T_ * D_)

typedef short bf16x8 __attribute__((ext_vector_type(8)));
typedef _Float16 f16x8 __attribute__((ext_vector_type(8)));
typedef float f32x4 __attribute__((ext_vector_type(4)));

__device__ __forceinline__ unsigned short f2b(float f) {
  __hip_bfloat16 h = __float2bfloat16(f);
  return *reinterpret_cast<unsigned short*>(&h);
}
__device__ __forceinline__ unsigned short f2h(float f) {
  __half h = __float2half(f);
  return *reinterpret_cast<unsigned short*>(&h);
}

__device__ __forceinline__ void gload16(const unsigned short* g, unsigned short* l) {
  __builtin_amdgcn_global_load_lds(
      (const __attribute__((address_space(1))) unsigned int*)(const void*)g,
      (__attribute__((address_space(3))) unsigned int*)(void*)l, 16, 0, 0);
}

// tanh-approx GELU via sigmoid identity: 0.5*(1+tanh(z)) = sigmoid(2z).
__device__ __forceinline__ float gelu_f(float x) {
  float z2 = 1.5957691216057308f * (x + 0.044715f * x * x * x);
  return x / (1.0f + __expf(-z2));
}

// ---------------- block reductions (256 threads, wave64) ----------------
__device__ __forceinline__ float blk_sum256(float v, float* s4) {
#pragma unroll
  for (int off = 32; off > 0; off >>= 1) v += __shfl_down(v, off);
  if ((threadIdx.x & 63) == 0) s4[threadIdx.x >> 6] = v;
  __syncthreads();
  float t = s4[0] + s4[1] + s4[2] + s4[3];
  __syncthreads();
  return t;
}

// ---------------- LayerNorm rows of D=1024, fp32 out + optional bf16 out ----
__global__ __launch_bounds__(256) void ln_rows(
    const float* __restrict__ in, const float* __restrict__ in2,
    const float* __restrict__ g, const float* __restrict__ bb,
    float* __restrict__ outf, unsigned short* __restrict__ outb) {
  __shared__ float s4[4];
  const size_t base = (size_t)blockIdx.x * D_;
  const int t = threadIdx.x;
  float4 v = ((const float4*)(in + base))[t];
  if (in2) {
    float4 w = ((const float4*)(in2 + base))[t];
    v.x += w.x; v.y += w.y; v.z += w.z; v.w += w.w;
  }
  float mean = blk_sum256(v.x + v.y + v.z + v.w, s4) * (1.0f / D_);
  float dx = v.x - mean, dy = v.y - mean, dz = v.z - mean, dw = v.w - mean;
  float var = blk_sum256(dx * dx + dy * dy + dz * dz + dw * dw, s4) * (1.0f / D_);
  float rstd = rsqrtf(var + 1e-5f);
  float4 gv = ((const float4*)g)[t];
  float4 bv = ((const float4*)bb)[t];
  float4 o;
  o.x = dx * rstd * gv.x + bv.x;
  o.y = dy * rstd * gv.y + bv.y;
  o.z = dz * rstd * gv.z + bv.z;
  o.w = dw * rstd * gv.w + bv.w;
  if (outf) ((float4*)(outf + base))[t] = o;
  if (outb) {
    unsigned short o4[4] = {f2b(o.x), f2b(o.y), f2b(o.z), f2b(o.w)};
    *(uint2*)(&outb[base + (size_t)t * 4]) = *(uint2*)o4;
  }
}

// ---------------- transpose+cast fp32 [R][C] -> bf16 [C][R] ----------------
__global__ __launch_bounds__(256) void tcast_t(
    const float* __restrict__ in, unsigned short* __restrict__ out, int R, int C) {
  __shared__ unsigned short tile[32][33];
  const int c0 = blockIdx.x * 32, r0 = blockIdx.y * 32;
  const int col = threadIdx.x & 31, rq = threadIdx.x >> 5;
#pragma unroll
  for (int i = 0; i < 4; ++i) {
    int r = rq + i * 8;
    tile[r][col] = f2b(in[(size_t)(r0 + r) * C + c0 + col]);
  }
  __syncthreads();
#pragma unroll
  for (int i = 0; i < 4; ++i) {
    int r = rq + i * 8;
    out[(size_t)(c0 + r) * R + r0 + col] = tile[col][r];
  }
}

// four 1024x1024 weights at once (z selects)
__global__ __launch_bounds__(256) void tcast4(
    const float* w0, const float* w1, const float* w2, const float* w3,
    unsigned short* o0, unsigned short* o1, unsigned short* o2, unsigned short* o3) {
  __shared__ unsigned short tile[32][33];
  const float* in = blockIdx.z == 0 ? w0 : blockIdx.z == 1 ? w1 : blockIdx.z == 2 ? w2 : w3;
  unsigned short* out = blockIdx.z == 0 ? o0 : blockIdx.z == 1 ? o1 : blockIdx.z == 2 ? o2 : o3;
  const int c0 = blockIdx.x * 32, r0 = blockIdx.y * 32;
  const int col = threadIdx.x & 31, rq = threadIdx.x >> 5;
#pragma unroll
  for (int i = 0; i < 4; ++i) {
    int r = rq + i * 8;
    tile[r][col] = f2b(in[(size_t)(r0 + r) * D_ + c0 + col]);
  }
  __syncthreads();
#pragma unroll
  for (int i = 0; i < 4; ++i) {
    int r = rq + i * 8;
    out[(size_t)(c0 + r) * D_ + r0 + col] = tile[col][r];
  }
}

// ---------------- fused attention: scores + softmax + ctx -------------------
// grid (64, 16): x = bh (XCD = bh%8 -> K/V L2-resident), y = t-tile (64 rows).
// m201-style schedule: raw barriers + counted vmcnt; K/V double-buffered so
// attn stores retire lazily across iterations (never vmcnt(0) in the loop).
// LDS 40 KB (5 x 8 KB regions) -> 4 blocks/CU.
__global__ __launch_bounds__(256, 4) void attn_fused(
    const unsigned short* __restrict__ qh, const unsigned short* __restrict__ kh,
    const unsigned short* __restrict__ vt, float* __restrict__ attn,
    unsigned short* __restrict__ ctxb) {
  __shared__ __align__(16) unsigned short L[5 * 4096];
  unsigned short* const R0 = L;            // Qs; phase-B K-odd buf
  unsigned short* const R1 = L + 4096;     // K-even buf
  unsigned short* const R2 = L + 2 * 4096; // phase-A K-odd buf; phase-B V-even
  unsigned short* const R3 = L + 3 * 4096; // phase-B V-odd buf
  unsigned short* const R4 = L + 4 * 4096; // Ps (sL aliases head)
  const int tid = threadIdx.x;
  const int l = tid & 63, w = tid >> 6;
  const int wm = w >> 1, wn = w & 1;
  const int lk = l >> 4, lr = l & 15;
  const int bh = blockIdx.x, b = bh >> 4, h = bh & 15;
  const int tt = blockIdx.y;
  const unsigned short* Qg = qh + (size_t)b * T_ * D_ + h * DH_ + (size_t)tt * 64 * D_;
  const unsigned short* Kg = kh + (size_t)b * T_ * D_ + h * DH_;
  const unsigned short* Vg = vt + (size_t)bh * 64 * T_;

  const int ar = tid >> 3, ac = tid & 7;
  const int aswz = ((ac ^ (ar & 7)) << 3);

  auto stageK = [&](int st, unsigned short* buf) {
#pragma unroll
    for (int i = 0; i < 2; ++i)
      gload16(Kg + (size_t)(st * 64 + ar + 32 * i) * D_ + aswz, &buf[(size_t)(i * 256 + tid) * 8]);
  };
  auto stageV = [&](int st, unsigned short* buf) {
#pragma unroll
    for (int i = 0; i < 2; ++i)
      gload16(Vg + (size_t)(ar + 32 * i) * T_ + st * 64 + aswz, &buf[(size_t)(i * 256 + tid) * 8]);
  };

  // prologue: Q -> R0 (2 loads), K0 -> R1 (2 loads)
#pragma unroll
  for (int i = 0; i < 2; ++i)
    gload16(Qg + (size_t)(ar + 32 * i) * D_ + aswz, &R0[(size_t)(i * 256 + tid) * 8]);
  stageK(0, R1);
  asm volatile("s_waitcnt vmcnt(2)" ::: "memory");  // Q landed (K0 may pend)
  __builtin_amdgcn_s_barrier();
  __builtin_amdgcn_sched_barrier(0);
  f16x8 qf[2][2];
#pragma unroll
  for (int mi = 0; mi < 2; ++mi) {
    const int row = wm * 32 + mi * 16 + lr;
#pragma unroll
    for (int kk = 0; kk < 2; ++kk)
      qf[mi][kk] = *(const f16x8*)&R0[row * 64 + (((kk * 4 + lk) ^ (row & 7)) << 3)];
  }

  float lsum[2][4] = {};  // per-LANE partial exp-sums; lr-reduce deferred

  // ---- phase A: row exp-sums (K dbuf R1/R2, 1-deep prefetch) ----
  for (int st = 0; st < 16; ++st) {
    asm volatile("s_waitcnt lgkmcnt(0)" ::: "memory");  // my LDS reads retired
    __builtin_amdgcn_s_barrier();
    __builtin_amdgcn_sched_barrier(0);
    if (st + 1 < 16) stageK(st + 1, ((st + 1) & 1) ? R2 : R1);
    __builtin_amdgcn_sched_barrier(0);
    if (st + 1 < 16) asm volatile("s_waitcnt vmcnt(2)" ::: "memory");
    else             asm volatile("s_waitcnt vmcnt(0)" ::: "memory");
    __builtin_amdgcn_sched_barrier(0);
    const unsigned short* Kb = (st & 1) ? R2 : R1;
    f16x8 kf[2][2];
#pragma unroll
    for (int ni = 0; ni < 2; ++ni) {
      const int row = wn * 32 + ni * 16 + lr;
#pragma unroll
      for (int kk = 0; kk < 2; ++kk)
        kf[ni][kk] = *(const f16x8*)&Kb[row * 64 + (((kk * 4 + lk) ^ (row & 7)) << 3)];
    }
    f32x4 acc[2][2] = {};
#pragma unroll
    for (int kk = 0; kk < 2; ++kk)
#pragma unroll
      for (int mi = 0; mi < 2; ++mi)
#pragma unroll
        for (int ni = 0; ni < 2; ++ni)
          acc[mi][ni] = __builtin_amdgcn_mfma_f32_16x16x32_f16(
              qf[mi][kk], kf[ni][kk], acc[mi][ni], 0, 0, 0);
#pragma unroll
    for (int mi = 0; mi < 2; ++mi)
#pragma unroll
      for (int r = 0; r < 4; ++r)
        lsum[mi][r] += __expf(acc[mi][0][r] * 0.125f) + __expf(acc[mi][1][r] * 0.125f);
  }
  // deferred lr-reduce (sum is linear in tiles)
#pragma unroll
  for (int mi = 0; mi < 2; ++mi)
#pragma unroll
    for (int r = 0; r < 4; ++r) {
      float v = lsum[mi][r];
      v += __shfl_xor(v, 1); v += __shfl_xor(v, 2);
      v += __shfl_xor(v, 4); v += __shfl_xor(v, 8);
      lsum[mi][r] = v;
    }

  // ---- cross-wave combine of the two wn-halves (sL aliases head of Ps) ----
  float* sL = (float*)R4;
  if (lr == 0) {
#pragma unroll
    for (int mi = 0; mi < 2; ++mi)
#pragma unroll
      for (int r = 0; r < 4; ++r)
        sL[wn * 64 + wm * 32 + mi * 16 + lk * 4 + r] = lsum[mi][r];
  }
  asm volatile("s_waitcnt lgkmcnt(0)" ::: "memory");
  __builtin_amdgcn_s_barrier();
  __builtin_amdgcn_sched_barrier(0);
  float rl[2][4];
#pragma unroll
  for (int mi = 0; mi < 2; ++mi)
#pragma unroll
    for (int r = 0; r < 4; ++r) {
      const int row = wm * 32 + mi * 16 + lk * 4 + r;
      rl[mi][r] = 1.0f / (sL[row] + sL[64 + row]);
    }
  asm volatile("s_waitcnt lgkmcnt(0)" ::: "memory");  // sL reads retired
  __builtin_amdgcn_sched_barrier(0);
  // phase-B prologue: K0 -> R1, V0 -> R2 (4 loads; not drained by any barrier)
  stageK(0, R1);
  stageV(0, R2);
  __builtin_amdgcn_sched_barrier(0);

  // ---- phase B: recompute, normalize, write attn, PV ----
  // vmcnt discipline (FIFO): at iter st's wait, newer ops = stores(st-1)[16] +
  // stage(st+1)[4] -> vmcnt(20); st=0 -> 4; st=15 (no stage) -> 16.
  float* Cg = attn + (size_t)bh * T_ * T_;
  f32x4 cacc[2][2] = {};
  for (int st = 0; st < 16; ++st) {
    asm volatile("s_waitcnt lgkmcnt(0)" ::: "memory");  // PV reads retired
    __builtin_amdgcn_s_barrier();                       // barrier1
    __builtin_amdgcn_sched_barrier(0);
    if (st + 1 < 16) {
      stageK(st + 1, ((st + 1) & 1) ? R0 : R1);
      stageV(st + 1, ((st + 1) & 1) ? R3 : R2);
    }
    __builtin_amdgcn_sched_barrier(0);
    if (st == 0)      asm volatile("s_waitcnt vmcnt(4)" ::: "memory");
    else if (st < 15) asm volatile("s_waitcnt vmcnt(20)" ::: "memory");
    else              asm volatile("s_waitcnt vmcnt(16)" ::: "memory");
    __builtin_amdgcn_sched_barrier(0);
    const unsigned short* Kb = (st & 1) ? R0 : R1;
    const unsigned short* Vb = (st & 1) ? R3 : R2;
    f16x8 kf[2][2], vf[2][2];
#pragma unroll
    for (int ni = 0; ni < 2; ++ni) {
      const int row = wn * 32 + ni * 16 + lr;
#pragma unroll
      for (int kk = 0; kk < 2; ++kk) {
        kf[ni][kk] = *(const f16x8*)&Kb[row * 64 + (((kk * 4 + lk) ^ (row & 7)) << 3)];
        vf[ni][kk] = *(const f16x8*)&Vb[row * 64 + (((kk * 4 + lk) ^ (row & 7)) << 3)];
      }
    }
    f32x4 acc[2][2] = {};
#pragma unroll
    for (int kk = 0; kk < 2; ++kk)
#pragma unroll
      for (int mi = 0; mi < 2; ++mi)
#pragma unroll
        for (int ni = 0; ni < 2; ++ni)
          acc[mi][ni] = __builtin_amdgcn_mfma_f32_16x16x32_f16(
              qf[mi][kk], kf[ni][kk], acc[mi][ni], 0, 0, 0);
    // normalize, write fp32 attn (nontemporal; retires lazily), stash f16 P
#pragma unroll
    for (int mi = 0; mi < 2; ++mi) {
      const int trow = wm * 32 + mi * 16 + lk * 4;
#pragma unroll
      for (int ni = 0; ni < 2; ++ni) {
        const int scol = wn * 32 + ni * 16 + lr;
#pragma unroll
        for (int r = 0; r < 4; ++r) {
          const int t = trow + r;
          float p = __expf(acc[mi][ni][r] * 0.125f) * rl[mi][r];
          __builtin_nontemporal_store(
              p, &Cg[(size_t)(tt * 64 + t) * T_ + (st * 64 + scol)]);
          R4[t * 64 + (scol ^ ((t & 7) << 3))] = f2h(p);
        }
      }
    }
    asm volatile("s_waitcnt lgkmcnt(0)" ::: "memory");  // Ps writes visible
    __builtin_amdgcn_s_barrier();                       // barrier2
    __builtin_amdgcn_sched_barrier(0);
    // PV: ctx[t][j] += P[t][s] * vt[j][s]
#pragma unroll
    for (int kk = 0; kk < 2; ++kk) {
      f16x8 af[2];
#pragma unroll
      for (int mi = 0; mi < 2; ++mi) {
        const int row = wm * 32 + mi * 16 + lr;
        af[mi] = *(const f16x8*)&R4[row * 64 + (((kk * 4 + lk) ^ (row & 7)) << 3)];
      }
#pragma unroll
      for (int mi = 0; mi < 2; ++mi)
#pragma unroll
        for (int ni = 0; ni < 2; ++ni)
          cacc[mi][ni] = __builtin_amdgcn_mfma_f32_16x16x32_f16(
              af[mi], vf[ni][kk], cacc[mi][ni], 0, 0, 0);
    }
  }

  unsigned short* Cb = ctxb + (size_t)b * T_ * D_ + h * DH_;
  const int crow0 = tt * 64 + wm * 32 + lk * 4;
  const int ccol0 = wn * 32 + lr;
#pragma unroll
  for (int mi = 0; mi < 2; ++mi)
#pragma unroll
    for (int ni = 0; ni < 2; ++ni)
#pragma unroll
      for (int r = 0; r < 4; ++r)
        Cb[(size_t)(crow0 + mi * 16 + r) * D_ + ccol0 + ni * 16] = f2b(cacc[mi][ni][r]);
}

// ---------------- MFMA NT GEMM: C[M][N] = A[M][K] @ Bn[N][K]^T ----------------
// EPI: 0=bias, 1=bias+gelu, 2=bias+res1, 3=scale only, 4=bias+res1+res2,
//      5=bias + f16 write TRANSPOSED per head: vt[(b*16+h)*64 + j][t]
// DB: 4-buffer, 3-tiles-in-flight pipeline with counted vmcnt.
template <int BN, int EPI, bool WF32, bool W16, bool FP16 = false, bool DB = false>
__global__ __launch_bounds__(256) void gemm_nt(
    const unsigned short* __restrict__ A, int lda,
    const unsigned short* __restrict__ Bm, int ldb,
    float* __restrict__ Cf, unsigned short* __restrict__ Cb, int ldc,
    const float* __restrict__ bias, const float* __restrict__ r1,
    const float* __restrict__ r2, float scale, int K) {
  constexpr int BM = 128, BK = 64;
  constexpr int WN = BN / 2;
  constexpr int FN = WN / 16;
  constexpr int NB = DB ? 4 : 1;
  static_assert(!DB || BN == 128, "counted vmcnt constants assume 8 loads/stage");
  __shared__ __align__(16) unsigned short As[NB][BM * BK];
  __shared__ __align__(16) unsigned short Bs[NB][BN * BK];
  const int tid = threadIdx.x;
  const int l = tid & 63;
  const int w = tid >> 6;
  const int wm = w >> 1, wn = w & 1;
  const int lr = l & 15, lk = l >> 4;
  const unsigned short* Ab = A + (size_t)blockIdx.y * BM * lda;
  const unsigned short* Bb = Bm + (size_t)blockIdx.x * BN * ldb;

  const int ar = tid >> 3;
  const int ac = tid & 7;
  const int aswz = ((ac ^ (ar & 7)) << 3);

  f32x4 acc[4][FN] = {};

  auto stage = [&](int buf, int k0) {
#pragma unroll
    for (int i = 0; i < 4; ++i)
      gload16(Ab + (size_t)(ar + 32 * i) * lda + k0 + aswz, &As[buf][(size_t)(i * 256 + tid) * 8]);
#pragma unroll
    for (int i = 0; i < BN / 32; ++i)
      gload16(Bb + (size_t)(ar + 32 * i) * ldb + k0 + aswz, &Bs[buf][(size_t)(i * 256 + tid) * 8]);
  };
  auto compute = [&](int buf) {
    bf16x8 af[4][2], bfr[FN][2];
#pragma unroll
    for (int mi = 0; mi < 4; ++mi) {
      const int row = wm * 64 + mi * 16 + lr;
#pragma unroll
      for (int kk = 0; kk < 2; ++kk)
        af[mi][kk] = *(const bf16x8*)&As[buf][row * BK + (((kk * 4 + lk) ^ (row & 7)) << 3)];
    }
#pragma unroll
    for (int ni = 0; ni < FN; ++ni) {
      const int row = wn * WN + ni * 16 + lr;
#pragma unroll
      for (int kk = 0; kk < 2; ++kk)
        bfr[ni][kk] = *(const bf16x8*)&Bs[buf][row * BK + (((kk * 4 + lk) ^ (row & 7)) << 3)];
    }
#pragma unroll
    for (int kk = 0; kk < 2; ++kk)
#pragma unroll
      for (int mi = 0; mi < 4; ++mi)
#pragma unroll
        for (int ni = 0; ni < FN; ++ni)
          acc[mi][ni] = __builtin_amdgcn_mfma_f32_16x16x32_bf16(
              af[mi][kk], bfr[ni][kk], acc[mi][ni], 0, 0, 0);
  };

  if constexpr (DB) {
    const int nt = K / BK;
    stage(0, 0);
    stage(1, BK);
    stage(2, 2 * BK);
    for (int t = 0; t < nt; ++t) {
      const int rem = nt - 1 - t;
      if (rem >= 2)      asm volatile("s_waitcnt vmcnt(16)" ::: "memory");
      else if (rem == 1) asm volatile("s_waitcnt vmcnt(8)" ::: "memory");
      else               asm volatile("s_waitcnt vmcnt(0)" ::: "memory");
      __builtin_amdgcn_s_barrier();
      __builtin_amdgcn_sched_barrier(0);
      if (t + 3 < nt) stage((t + 3) & 3, (t + 3) * BK);
      compute(t & 3);
    }
  } else {
    for (int k0 = 0; k0 < K; k0 += BK) {
      stage(0, k0);
      __syncthreads();
      compute(0);
      __syncthreads();
    }
  }

  const int crow0 = blockIdx.y * BM + wm * 64 + lk * 4;
  const int ccol0 = blockIdx.x * BN + wn * WN + lr;
  if constexpr (EPI == 5) {
#pragma unroll
    for (int mi = 0; mi < 4; ++mi)
#pragma unroll
      for (int ni = 0; ni < FN; ++ni) {
        const int row0 = crow0 + mi * 16;
        const int col = ccol0 + ni * 16;
        unsigned short __attribute__((aligned(8))) p4[4];
#pragma unroll
        for (int r = 0; r < 4; ++r) p4[r] = f2h(acc[mi][ni][r] + bias[col]);
        const int bidx = row0 >> 10, t0 = row0 & 1023;
        const int hh = col >> 6, j = col & 63;
        *(uint2*)&Cb[(((size_t)bidx * 16 + hh) * 64 + j) * T_ + t0] = *(uint2*)p4;
      }
  } else {
#pragma unroll
    for (int mi = 0; mi < 4; ++mi)
#pragma unroll
      for (int ni = 0; ni < FN; ++ni)
#pragma unroll
        for (int r = 0; r < 4; ++r) {
          const int row = crow0 + mi * 16 + r;
          const int col = ccol0 + ni * 16;
          float v = acc[mi][ni][r] * scale;
          if (EPI != 3) v += bias[col];
          if (EPI == 1) v = gelu_f(v);
          const size_t off = (size_t)row * ldc + col;
          if (EPI == 2) v += r1[off];
          if (EPI == 4) v += r1[off] + r2[off];
          if (WF32) Cf[off] = v;
          if (W16) Cb[off] = FP16 ? f2h(v) : f2b(v);
        }
  }
}

// ---------------- fused QKV: one N=3072 GEMM over contiguous WqT|WkT|WvT ----
__global__ __launch_bounds__(256) void gemm_qkv(
    const unsigned short* __restrict__ A, const unsigned short* __restrict__ Wt,
    const float* __restrict__ bq, const float* __restrict__ bk,
    const float* __restrict__ bv, const float* __restrict__ sp,
    const float* __restrict__ ed, unsigned short* __restrict__ q_h,
    unsigned short* __restrict__ kb_h, unsigned short* __restrict__ vt) {
  constexpr int BM = 128, BN = 128, BK = 64, K = 1024;
  __shared__ __align__(16) unsigned short As[BM * BK];
  __shared__ __align__(16) unsigned short Bs[BN * BK];
  const int tid = threadIdx.x;
  const int l = tid & 63, w = tid >> 6;
  const int wm = w >> 1, wn = w & 1;
  const int lr = l & 15, lk = l >> 4;
  const unsigned short* Ab = A + (size_t)blockIdx.y * BM * D_;
  const unsigned short* Bb = Wt + (size_t)blockIdx.x * BN * D_;
  const int ar = tid >> 3, ac = tid & 7;
  const int aswz = ((ac ^ (ar & 7)) << 3);

  f32x4 acc[4][4] = {};
  for (int k0 = 0; k0 < K; k0 += BK) {
#pragma unroll
    for (int i = 0; i < 4; ++i) {
      gload16(Ab + (size_t)(ar + 32 * i) * D_ + k0 + aswz, &As[(size_t)(i * 256 + tid) * 8]);
      gload16(Bb + (size_t)(ar + 32 * i) * D_ + k0 + aswz, &Bs[(size_t)(i * 256 + tid) * 8]);
    }
    __syncthreads();
    bf16x8 af[4][2], bfr[4][2];
#pragma unroll
    for (int mi = 0; mi < 4; ++mi) {
      const int row = wm * 64 + mi * 16 + lr;
#pragma unroll
      for (int kk = 0; kk < 2; ++kk)
        af[mi][kk] = *(const bf16x8*)&As[row * BK + (((kk * 4 + lk) ^ (row & 7)) << 3)];
    }
#pragma unroll
    for (int ni = 0; ni < 4; ++ni) {
      const int row = wn * 64 + ni * 16 + lr;
#pragma unroll
      for (int kk = 0; kk < 2; ++kk)
        bfr[ni][kk] = *(const bf16x8*)&Bs[row * BK + (((kk * 4 + lk) ^ (row & 7)) << 3)];
    }
#pragma unroll
    for (int kk = 0; kk < 2; ++kk)
#pragma unroll
      for (int mi = 0; mi < 4; ++mi)
#pragma unroll
        for (int ni = 0; ni < 4; ++ni)
          acc[mi][ni] = __builtin_amdgcn_mfma_f32_16x16x32_bf16(
              af[mi][kk], bfr[ni][kk], acc[mi][ni], 0, 0, 0);
    __syncthreads();
  }

  const int seg = blockIdx.x >> 3;  // 0=Q, 1=K, 2=V
  const float* bias = seg == 0 ? bq : seg == 1 ? bk : bv;
  const int crow0 = blockIdx.y * BM + wm * 64 + lk * 4;
  const int ccol0 = blockIdx.x * BN + wn * 64 + lr;
  if (seg == 2) {
#pragma unroll
    for (int mi = 0; mi < 4; ++mi)
#pragma unroll
      for (int ni = 0; ni < 4; ++ni) {
        const int row0 = crow0 + mi * 16;
        const int col = (ccol0 + ni * 16) & 1023;
        unsigned short __attribute__((aligned(8))) p4[4];
#pragma unroll
        for (int r = 0; r < 4; ++r) p4[r] = f2h(acc[mi][ni][r] + bias[col]);
        const int bidx = row0 >> 10, t0 = row0 & 1023;
        const int hh = col >> 6, j = col & 63;
        *(uint2*)&vt[(((size_t)bidx * 16 + hh) * 64 + j) * T_ + t0] = *(uint2*)p4;
      }
  } else {
    unsigned short* out = seg == 0 ? q_h : kb_h;
#pragma unroll
    for (int mi = 0; mi < 4; ++mi)
#pragma unroll
      for (int ni = 0; ni < 4; ++ni)
#pragma unroll
        for (int r = 0; r < 4; ++r) {
          const int row = crow0 + mi * 16 + r;
          const int col = (ccol0 + ni * 16) & 1023;
          float v = acc[mi][ni][r] + bias[col];
          const size_t off = (size_t)row * D_ + col;
          if (seg == 1) v += sp[off] + ed[off];
          out[off] = f2h(v);
        }
  }
}

extern "C" void kernel_launch(void* const* d_in, const int* in_sizes, int n_in,
                              void* d_out, int out_size, void* d_ws, size_t ws_size,
                              hipStream_t stream) {
  const float* x    = (const float*)d_in[0];
  const float* sp   = (const float*)d_in[1];
  const float* ed   = (const float*)d_in[2];
  const float* ln1g = (const float*)d_in[3];
  const float* ln1b = (const float*)d_in[4];
  const float* Wq   = (const float*)d_in[5];
  const float* bq   = (const float*)d_in[6];
  const float* Wk   = (const float*)d_in[7];
  const float* bk   = (const float*)d_in[8];
  const float* Wv   = (const float*)d_in[9];
  const float* bvv  = (const float*)d_in[10];
  const float* Wo   = (const float*)d_in[11];
  const float* bo   = (const float*)d_in[12];
  const float* ln2g = (const float*)d_in[13];
  const float* ln2b = (const float*)d_in[14];
  const float* W1   = (const float*)d_in[15];
  const float* b1   = (const float*)d_in[16];
  const float* W2   = (const float*)d_in[17];
  const float* b2   = (const float*)d_in[18];
  const float* lnbg = (const float*)d_in[19];
  const float* lnbb = (const float*)d_in[20];

  float* out_x = (float*)d_out;
  float* attn  = out_x + BTD;
  float* tt    = out_x;

  const size_t MB = 1 << 20;
  char* wsb = (char*)d_ws;
  float*          xn    = (float*)(wsb);                    // [0,16)
  unsigned short* xn_b  = (unsigned short*)(wsb + 16 * MB); // [16,24)
  unsigned short* WqT   = (unsigned short*)(wsb + 24 * MB); // [24,30) Wq|Wk|Wv
  unsigned short* WkT   = (unsigned short*)(wsb + 26 * MB);
  unsigned short* WvT   = (unsigned short*)(wsb + 28 * MB);
  unsigned short* WoT   = (unsigned short*)(wsb + 30 * MB);
  unsigned short* W1T   = (unsigned short*)(wsb + 32 * MB); // [32,40)
  unsigned short* W2T   = (unsigned short*)(wsb + 40 * MB); // [40,48)
  unsigned short* q_h   = (unsigned short*)(wsb + 48 * MB); // [48,56)
  unsigned short* kb_h  = (unsigned short*)(wsb + 56 * MB); // [56,64)
  unsigned short* vt    = (unsigned short*)(wsb + 80 * MB); // [80,88)
  unsigned short* ctx_b = xn_b;                             // [16,24)
  unsigned short* h1_b  = (unsigned short*)(wsb + 48 * MB); // [48,80)
  float*          h2    = (float*)(wsb + 80 * MB);          // [80,96)
  float*          y     = xn;
  unsigned short* y_b   = xn_b;

  dim3 blk(256);
  dim3 g_dd(8, 32);

  // 1. LN1 -> xn (fp32 residual) + xn_b (bf16 GEMM operand)
  ln_rows<<<BT_, blk, 0, stream>>>(x, nullptr, ln1g, ln1b, xn, xn_b);
  // 2. weight transpose+cast
  tcast4<<<dim3(32, 32, 4), blk, 0, stream>>>(Wq, Wk, Wv, Wo, WqT, WkT, WvT, WoT);
  tcast_t<<<dim3(128, 32), blk, 0, stream>>>(W1, W1T, 1024, 4096);
  tcast_t<<<dim3(32, 128), blk, 0, stream>>>(W2, W2T, 4096, 1024);
  // 3. fused QKV (768 blocks): Q->f16, K(+sp+ed)->f16, V->f16 transposed
  gemm_qkv<<<dim3(24, 32), blk, 0, stream>>>(
      xn_b, WqT, bq, bk, bvv, sp, ed, q_h, kb_h, vt);
  // 4. fused scores + softmax + ctx (1024 blocks, 4/CU, counted-vmcnt schedule)
  attn_fused<<<dim3(64, 16), blk, 0, stream>>>(q_h, kb_h, vt, attn, ctx_b);
  // 5. tt = ctx @ Wo + bo + xn (MFMA, 4-deep counted-vmcnt pipeline)
  gemm_nt<128, 2, true, false, false, true><<<g_dd, blk, 0, stream>>>(
      ctx_b, D_, WoT, D_, tt, nullptr, D_, bo, xn, nullptr, 1.f, D_);
  // 6. y = LN2(tt)
  ln_rows<<<BT_, blk, 0, stream>>>(tt, nullptr, ln2g, ln2b, y, y_b);
  // 7. h1 = gelu(y @ W1 + b1) -> bf16 (MFMA, 1024 blocks single-buffer)
  gemm_nt<128, 1, false, true><<<dim3(32, 32), blk, 0, stream>>>(
      y_b, D_, W1T, D_, nullptr, h1_b, F_, b1, nullptr, nullptr, 1.f, D_);
  // 8. h2 = y + (h1 @ W2 + b2)  (MFMA, 4-deep counted-vmcnt pipeline)
  gemm_nt<128, 2, true, false, false, true><<<g_dd, blk, 0, stream>>>(
      h1_b, F_, W2T, F_, h2, nullptr, D_, b2, y, nullptr, 1.f, F_);
  // 9. out = LN(h2)
  ln_rows<<<BT_, blk, 0, stream>>>(h2, nullptr, lnbg, lnbb, out_x, nullptr);
}

// Round 17
// 341.927 us; speedup vs baseline: 1.1183x; 1.0427x over previous
//
#include <hip/hip_runtime.h>
#include <hip/hip_bf16.h>
#include <hip/hip_fp16.h>
#include <math.h>

#define B_ 4
#define T_ 1024
#define D_ 1024
#define H_ 16
#define DH_ 64
#define F_ 4096
#define BT_ (B_ * T_)
#define BTD ((size_t)B_ * T_ * D_)

typedef short bf16x8 __attribute__((ext_vector_type(8)));
typedef _Float16 f16x8 __attribute__((ext_vector_type(8)));
typedef float f32x4 __attribute__((ext_vector_type(4)));

__device__ __forceinline__ unsigned short f2b(float f) {
  __hip_bfloat16 h = __float2bfloat16(f);
  return *reinterpret_cast<unsigned short*>(&h);
}
__device__ __forceinline__ unsigned short f2h(float f) {
  __half h = __float2half(f);
  return *reinterpret_cast<unsigned short*>(&h);
}

__device__ __forceinline__ void gload16(const unsigned short* g, unsigned short* l) {
  __builtin_amdgcn_global_load_lds(
      (const __attribute__((address_space(1))) unsigned int*)(const void*)g,
      (__attribute__((address_space(3))) unsigned int*)(void*)l, 16, 0, 0);
}

// tanh-approx GELU via sigmoid identity: 0.5*(1+tanh(z)) = sigmoid(2z).
__device__ __forceinline__ float gelu_f(float x) {
  float z2 = 1.5957691216057308f * (x + 0.044715f * x * x * x);
  return x / (1.0f + __expf(-z2));
}

// ---------------- block reductions (256 threads, wave64) ----------------
__device__ __forceinline__ float blk_sum256(float v, float* s4) {
#pragma unroll
  for (int off = 32; off > 0; off >>= 1) v += __shfl_down(v, off);
  if ((threadIdx.x & 63) == 0) s4[threadIdx.x >> 6] = v;
  __syncthreads();
  float t = s4[0] + s4[1] + s4[2] + s4[3];
  __syncthreads();
  return t;
}

// ---------------- LayerNorm rows of D=1024, fp32 out + optional bf16 out ----
__global__ __launch_bounds__(256) void ln_rows(
    const float* __restrict__ in, const float* __restrict__ in2,
    const float* __restrict__ g, const float* __restrict__ bb,
    float* __restrict__ outf, unsigned short* __restrict__ outb) {
  __shared__ float s4[4];
  const size_t base = (size_t)blockIdx.x * D_;
  const int t = threadIdx.x;
  float4 v = ((const float4*)(in + base))[t];
  if (in2) {
    float4 w = ((const float4*)(in2 + base))[t];
    v.x += w.x; v.y += w.y; v.z += w.z; v.w += w.w;
  }
  float mean = blk_sum256(v.x + v.y + v.z + v.w, s4) * (1.0f / D_);
  float dx = v.x - mean, dy = v.y - mean, dz = v.z - mean, dw = v.w - mean;
  float var = blk_sum256(dx * dx + dy * dy + dz * dz + dw * dw, s4) * (1.0f / D_);
  float rstd = rsqrtf(var + 1e-5f);
  float4 gv = ((const float4*)g)[t];
  float4 bv = ((const float4*)bb)[t];
  float4 o;
  o.x = dx * rstd * gv.x + bv.x;
  o.y = dy * rstd * gv.y + bv.y;
  o.z = dz * rstd * gv.z + bv.z;
  o.w = dw * rstd * gv.w + bv.w;
  if (outf) ((float4*)(outf + base))[t] = o;
  if (outb) {
    unsigned short o4[4] = {f2b(o.x), f2b(o.y), f2b(o.z), f2b(o.w)};
    *(uint2*)(&outb[base + (size_t)t * 4]) = *(uint2*)o4;
  }
}

// ---------------- transpose+cast fp32 [R][C] -> bf16 [C][R] ----------------
__global__ __launch_bounds__(256) void tcast_t(
    const float* __restrict__ in, unsigned short* __restrict__ out, int R, int C) {
  __shared__ unsigned short tile[32][33];
  const int c0 = blockIdx.x * 32, r0 = blockIdx.y * 32;
  const int col = threadIdx.x & 31, rq = threadIdx.x >> 5;
#pragma unroll
  for (int i = 0; i < 4; ++i) {
    int r = rq + i * 8;
    tile[r][col] = f2b(in[(size_t)(r0 + r) * C + c0 + col]);
  }
  __syncthreads();
#pragma unroll
  for (int i = 0; i < 4; ++i) {
    int r = rq + i * 8;
    out[(size_t)(c0 + r) * R + r0 + col] = tile[col][r];
  }
}

// four 1024x1024 weights at once (z selects)
__global__ __launch_bounds__(256) void tcast4(
    const float* w0, const float* w1, const float* w2, const float* w3,
    unsigned short* o0, unsigned short* o1, unsigned short* o2, unsigned short* o3) {
  __shared__ unsigned short tile[32][33];
  const float* in = blockIdx.z == 0 ? w0 : blockIdx.z == 1 ? w1 : blockIdx.z == 2 ? w2 : w3;
  unsigned short* out = blockIdx.z == 0 ? o0 : blockIdx.z == 1 ? o1 : blockIdx.z == 2 ? o2 : o3;
  const int c0 = blockIdx.x * 32, r0 = blockIdx.y * 32;
  const int col = threadIdx.x & 31, rq = threadIdx.x >> 5;
#pragma unroll
  for (int i = 0; i < 4; ++i) {
    int r = rq + i * 8;
    tile[r][col] = f2b(in[(size_t)(r0 + r) * D_ + c0 + col]);
  }
  __syncthreads();
#pragma unroll
  for (int i = 0; i < 4; ++i) {
    int r = rq + i * 8;
    out[(size_t)(c0 + r) * D_ + r0 + col] = tile[col][r];
  }
}

// ---------------- fused attention: scores + softmax + ctx -------------------
// grid (64, 16): x = bh (XCD = bh%8 -> K/V L2-resident), y = t-tile (64 rows).
// Counted-vmcnt schedule. RACE FIX (r16): the per-wave vmcnt that certifies
// the CURRENT tile's loads must come BEFORE the barrier (each wave certifies
// its own loads; the barrier globalizes it). Stores still retire lazily.
__global__ __launch_bounds__(256, 4) void attn_fused(
    const unsigned short* __restrict__ qh, const unsigned short* __restrict__ kh,
    const unsigned short* __restrict__ vt, float* __restrict__ attn,
    unsigned short* __restrict__ ctxb) {
  __shared__ __align__(16) unsigned short L[5 * 4096];
  unsigned short* const R0 = L;            // Qs; phase-B K-odd
  unsigned short* const R1 = L + 4096;     // K-even
  unsigned short* const R2 = L + 2 * 4096; // phase-A K-odd; phase-B V-even
  unsigned short* const R3 = L + 3 * 4096; // phase-B V-odd
  unsigned short* const R4 = L + 4 * 4096; // Ps (sL aliases head)
  const int tid = threadIdx.x;
  const int l = tid & 63, w = tid >> 6;
  const int wm = w >> 1, wn = w & 1;
  const int lk = l >> 4, lr = l & 15;
  const int bh = blockIdx.x, b = bh >> 4, h = bh & 15;
  const int tt = blockIdx.y;
  const unsigned short* Qg = qh + (size_t)b * T_ * D_ + h * DH_ + (size_t)tt * 64 * D_;
  const unsigned short* Kg = kh + (size_t)b * T_ * D_ + h * DH_;
  const unsigned short* Vg = vt + (size_t)bh * 64 * T_;

  const int ar = tid >> 3, ac = tid & 7;
  const int aswz = ((ac ^ (ar & 7)) << 3);

  auto stageK = [&](int st, unsigned short* buf) {
#pragma unroll
    for (int i = 0; i < 2; ++i)
      gload16(Kg + (size_t)(st * 64 + ar + 32 * i) * D_ + aswz, &buf[(size_t)(i * 256 + tid) * 8]);
  };
  auto stageV = [&](int st, unsigned short* buf) {
#pragma unroll
    for (int i = 0; i < 2; ++i)
      gload16(Vg + (size_t)(ar + 32 * i) * T_ + st * 64 + aswz, &buf[(size_t)(i * 256 + tid) * 8]);
  };

  // prologue: Q -> R0, K0 -> R1. vmcnt BEFORE barrier certifies Q cross-wave.
#pragma unroll
  for (int i = 0; i < 2; ++i)
    gload16(Qg + (size_t)(ar + 32 * i) * D_ + aswz, &R0[(size_t)(i * 256 + tid) * 8]);
  stageK(0, R1);
  asm volatile("s_waitcnt vmcnt(2)" ::: "memory");  // my Q landed (K0 may pend)
  __builtin_amdgcn_s_barrier();
  __builtin_amdgcn_sched_barrier(0);
  f16x8 qf[2][2];
#pragma unroll
  for (int mi = 0; mi < 2; ++mi) {
    const int row = wm * 32 + mi * 16 + lr;
#pragma unroll
    for (int kk = 0; kk < 2; ++kk)
      qf[mi][kk] = *(const f16x8*)&R0[row * 64 + (((kk * 4 + lk) ^ (row & 7)) << 3)];
  }

  float lsum[2][4] = {};

  // ---- phase A: vmcnt(0) pre-barrier certifies stage(st); then prefetch ----
  for (int st = 0; st < 16; ++st) {
    asm volatile("s_waitcnt vmcnt(0) lgkmcnt(0)" ::: "memory");
    __builtin_amdgcn_s_barrier();
    __builtin_amdgcn_sched_barrier(0);
    if (st + 1 < 16) stageK(st + 1, ((st + 1) & 1) ? R2 : R1);
    __builtin_amdgcn_sched_barrier(0);
    const unsigned short* Kb = (st & 1) ? R2 : R1;
    f16x8 kf[2][2];
#pragma unroll
    for (int ni = 0; ni < 2; ++ni) {
      const int row = wn * 32 + ni * 16 + lr;
#pragma unroll
      for (int kk = 0; kk < 2; ++kk)
        kf[ni][kk] = *(const f16x8*)&Kb[row * 64 + (((kk * 4 + lk) ^ (row & 7)) << 3)];
    }
    f32x4 acc[2][2] = {};
#pragma unroll
    for (int kk = 0; kk < 2; ++kk)
#pragma unroll
      for (int mi = 0; mi < 2; ++mi)
#pragma unroll
        for (int ni = 0; ni < 2; ++ni)
          acc[mi][ni] = __builtin_amdgcn_mfma_f32_16x16x32_f16(
              qf[mi][kk], kf[ni][kk], acc[mi][ni], 0, 0, 0);
#pragma unroll
    for (int mi = 0; mi < 2; ++mi)
#pragma unroll
      for (int r = 0; r < 4; ++r)
        lsum[mi][r] += __expf(acc[mi][0][r] * 0.125f) + __expf(acc[mi][1][r] * 0.125f);
  }
#pragma unroll
  for (int mi = 0; mi < 2; ++mi)
#pragma unroll
    for (int r = 0; r < 4; ++r) {
      float v = lsum[mi][r];
      v += __shfl_xor(v, 1); v += __shfl_xor(v, 2);
      v += __shfl_xor(v, 4); v += __shfl_xor(v, 8);
      lsum[mi][r] = v;
    }

  // ---- cross-wave combine (sL aliases head of Ps) ----
  float* sL = (float*)R4;
  if (lr == 0) {
#pragma unroll
    for (int mi = 0; mi < 2; ++mi)
#pragma unroll
      for (int r = 0; r < 4; ++r)
        sL[wn * 64 + wm * 32 + mi * 16 + lk * 4 + r] = lsum[mi][r];
  }
  asm volatile("s_waitcnt lgkmcnt(0)" ::: "memory");
  __builtin_amdgcn_s_barrier();
  __builtin_amdgcn_sched_barrier(0);
  float rl[2][4];
#pragma unroll
  for (int mi = 0; mi < 2; ++mi)
#pragma unroll
    for (int r = 0; r < 4; ++r) {
      const int row = wm * 32 + mi * 16 + lk * 4 + r;
      rl[mi][r] = 1.0f / (sL[row] + sL[64 + row]);
    }
  asm volatile("s_waitcnt lgkmcnt(0)" ::: "memory");  // my sL reads retired
  __builtin_amdgcn_sched_barrier(0);
  // phase-B prologue: K0 -> R1, V0 -> R2 (certified at iter 0's pre-barrier wait)
  stageK(0, R1);
  stageV(0, R2);
  __builtin_amdgcn_sched_barrier(0);

  // ---- phase B ----
  // pre-barrier wait: st==0 -> vmcnt(0) (prologue only); st>=1 -> vmcnt(16):
  // per-wave issue order ... stage(st)[4], stores(st-1)[16] -> newest 16 are
  // stores; <=16 outstanding => stage(st) landed, stores may stay in flight.
  float* Cg = attn + (size_t)bh * T_ * T_;
  f32x4 cacc[2][2] = {};
  for (int st = 0; st < 16; ++st) {
    if (st == 0) asm volatile("s_waitcnt vmcnt(0) lgkmcnt(0)" ::: "memory");
    else         asm volatile("s_waitcnt vmcnt(16) lgkmcnt(0)" ::: "memory");
    __builtin_amdgcn_s_barrier();                       // barrier1
    __builtin_amdgcn_sched_barrier(0);
    if (st + 1 < 16) {
      stageK(st + 1, ((st + 1) & 1) ? R0 : R1);
      stageV(st + 1, ((st + 1) & 1) ? R3 : R2);
    }
    __builtin_amdgcn_sched_barrier(0);
    const unsigned short* Kb = (st & 1) ? R0 : R1;
    const unsigned short* Vb = (st & 1) ? R3 : R2;
    f16x8 kf[2][2], vf[2][2];
#pragma unroll
    for (int ni = 0; ni < 2; ++ni) {
      const int row = wn * 32 + ni * 16 + lr;
#pragma unroll
      for (int kk = 0; kk < 2; ++kk) {
        kf[ni][kk] = *(const f16x8*)&Kb[row * 64 + (((kk * 4 + lk) ^ (row & 7)) << 3)];
        vf[ni][kk] = *(const f16x8*)&Vb[row * 64 + (((kk * 4 + lk) ^ (row & 7)) << 3)];
      }
    }
    f32x4 acc[2][2] = {};
#pragma unroll
    for (int kk = 0; kk < 2; ++kk)
#pragma unroll
      for (int mi = 0; mi < 2; ++mi)
#pragma unroll
        for (int ni = 0; ni < 2; ++ni)
          acc[mi][ni] = __builtin_amdgcn_mfma_f32_16x16x32_f16(
              qf[mi][kk], kf[ni][kk], acc[mi][ni], 0, 0, 0);
#pragma unroll
    for (int mi = 0; mi < 2; ++mi) {
      const int trow = wm * 32 + mi * 16 + lk * 4;
#pragma unroll
      for (int ni = 0; ni < 2; ++ni) {
        const int scol = wn * 32 + ni * 16 + lr;
#pragma unroll
        for (int r = 0; r < 4; ++r) {
          const int t = trow + r;
          float p = __expf(acc[mi][ni][r] * 0.125f) * rl[mi][r];
          __builtin_nontemporal_store(
              p, &Cg[(size_t)(tt * 64 + t) * T_ + (st * 64 + scol)]);
          R4[t * 64 + (scol ^ ((t & 7) << 3))] = f2h(p);
        }
      }
    }
    asm volatile("s_waitcnt lgkmcnt(0)" ::: "memory");  // Ps writes visible
    __builtin_amdgcn_s_barrier();                       // barrier2
    __builtin_amdgcn_sched_barrier(0);
#pragma unroll
    for (int kk = 0; kk < 2; ++kk) {
      f16x8 af[2];
#pragma unroll
      for (int mi = 0; mi < 2; ++mi) {
        const int row = wm * 32 + mi * 16 + lr;
        af[mi] = *(const f16x8*)&R4[row * 64 + (((kk * 4 + lk) ^ (row & 7)) << 3)];
      }
#pragma unroll
      for (int mi = 0; mi < 2; ++mi)
#pragma unroll
        for (int ni = 0; ni < 2; ++ni)
          cacc[mi][ni] = __builtin_amdgcn_mfma_f32_16x16x32_f16(
              af[mi], vf[ni][kk], cacc[mi][ni], 0, 0, 0);
    }
  }

  unsigned short* Cb = ctxb + (size_t)b * T_ * D_ + h * DH_;
  const int crow0 = tt * 64 + wm * 32 + lk * 4;
  const int ccol0 = wn * 32 + lr;
#pragma unroll
  for (int mi = 0; mi < 2; ++mi)
#pragma unroll
    for (int ni = 0; ni < 2; ++ni)
#pragma unroll
      for (int r = 0; r < 4; ++r)
        Cb[(size_t)(crow0 + mi * 16 + r) * D_ + ccol0 + ni * 16] = f2b(cacc[mi][ni][r]);
}

// ---------------- MFMA NT GEMM: C[M][N] = A[M][K] @ Bn[N][K]^T ----------------
// EPI: 0=bias, 1=bias+gelu, 2=bias+res1, 3=scale only, 4=bias+res1+res2,
//      5=bias + f16 write TRANSPOSED per head.
// DB: 4-buffer, 3-tiles-in-flight counted-vmcnt pipeline (vmcnt pre-barrier).
// NT: threads/block. NT=512 -> 8 waves (2Mx4N) = 2 waves/SIMD at 1 block/CU.
template <int BN, int EPI, bool WF32, bool W16, bool FP16 = false, bool DB = false,
          int NT = 256>
__global__ __launch_bounds__(NT) void gemm_nt(
    const unsigned short* __restrict__ A, int lda,
    const unsigned short* __restrict__ Bm, int ldb,
    float* __restrict__ Cf, unsigned short* __restrict__ Cb, int ldc,
    const float* __restrict__ bias, const float* __restrict__ r1,
    const float* __restrict__ r2, float scale, int K) {
  constexpr int BM = 128, BK = 64;
  constexpr int WAVES = NT / 64;
  constexpr int WNC = WAVES / 2;
  constexpr int WN = BN / WNC;
  constexpr int FN = WN / 16;
  constexpr int NB = DB ? 4 : 1;
  constexpr int RS = NT / 8;
  constexpr int AI = BM / RS, BI = BN / RS;
  __shared__ __align__(16) unsigned short As[NB][BM * BK];
  __shared__ __align__(16) unsigned short Bs[NB][BN * BK];
  const int tid = threadIdx.x;
  const int l = tid & 63;
  const int w = tid >> 6;
  const int wm = w / WNC, wn = w % WNC;
  const int lr = l & 15, lk = l >> 4;
  const unsigned short* Ab = A + (size_t)blockIdx.y * BM * lda;
  const unsigned short* Bb = Bm + (size_t)blockIdx.x * BN * ldb;

  const int ar = tid >> 3;
  const int ac = tid & 7;
  const int aswz = ((ac ^ (ar & 7)) << 3);

  f32x4 acc[4][FN] = {};

  auto stage = [&](int buf, int k0) {
#pragma unroll
    for (int i = 0; i < AI; ++i)
      gload16(Ab + (size_t)(ar + RS * i) * lda + k0 + aswz, &As[buf][(size_t)(i * NT + tid) * 8]);
#pragma unroll
    for (int i = 0; i < BI; ++i)
      gload16(Bb + (size_t)(ar + RS * i) * ldb + k0 + aswz, &Bs[buf][(size_t)(i * NT + tid) * 8]);
  };
  auto compute = [&](int buf) {
    bf16x8 af[4][2], bfr[FN][2];
#pragma unroll
    for (int mi = 0; mi < 4; ++mi) {
      const int row = wm * 64 + mi * 16 + lr;
#pragma unroll
      for (int kk = 0; kk < 2; ++kk)
        af[mi][kk] = *(const bf16x8*)&As[buf][row * BK + (((kk * 4 + lk) ^ (row & 7)) << 3)];
    }
#pragma unroll
    for (int ni = 0; ni < FN; ++ni) {
      const int row = wn * WN + ni * 16 + lr;
#pragma unroll
      for (int kk = 0; kk < 2; ++kk)
        bfr[ni][kk] = *(const bf16x8*)&Bs[buf][row * BK + (((kk * 4 + lk) ^ (row & 7)) << 3)];
    }
#pragma unroll
    for (int kk = 0; kk < 2; ++kk)
#pragma unroll
      for (int mi = 0; mi < 4; ++mi)
#pragma unroll
        for (int ni = 0; ni < FN; ++ni)
          acc[mi][ni] = __builtin_amdgcn_mfma_f32_16x16x32_bf16(
              af[mi][kk], bfr[ni][kk], acc[mi][ni], 0, 0, 0);
  };

  if constexpr (DB) {
    const int nt = K / BK;
    stage(0, 0);
    stage(1, BK);
    stage(2, 2 * BK);
    for (int t = 0; t < nt; ++t) {
      const int rem = nt - 1 - t;
      if constexpr (AI + BI == 8) {
        if (rem >= 2)      asm volatile("s_waitcnt vmcnt(16)" ::: "memory");
        else if (rem == 1) asm volatile("s_waitcnt vmcnt(8)" ::: "memory");
        else               asm volatile("s_waitcnt vmcnt(0)" ::: "memory");
      } else {  // AI+BI == 4 (NT=512)
        if (rem >= 2)      asm volatile("s_waitcnt vmcnt(8)" ::: "memory");
        else if (rem == 1) asm volatile("s_waitcnt vmcnt(4)" ::: "memory");
        else               asm volatile("s_waitcnt vmcnt(0)" ::: "memory");
      }
      __builtin_amdgcn_s_barrier();
      __builtin_amdgcn_sched_barrier(0);
      if (t + 3 < nt) stage((t + 3) & 3, (t + 3) * BK);
      compute(t & 3);
    }
  } else {
    for (int k0 = 0; k0 < K; k0 += BK) {
      stage(0, k0);
      __syncthreads();
      compute(0);
      __syncthreads();
    }
  }

  const int crow0 = blockIdx.y * BM + wm * 64 + lk * 4;
  const int ccol0 = blockIdx.x * BN + wn * WN + lr;
  if constexpr (EPI == 5) {
#pragma unroll
    for (int mi = 0; mi < 4; ++mi)
#pragma unroll
      for (int ni = 0; ni < FN; ++ni) {
        const int row0 = crow0 + mi * 16;
        const int col = ccol0 + ni * 16;
        unsigned short __attribute__((aligned(8))) p4[4];
#pragma unroll
        for (int r = 0; r < 4; ++r) p4[r] = f2h(acc[mi][ni][r] + bias[col]);
        const int bidx = row0 >> 10, t0 = row0 & 1023;
        const int hh = col >> 6, j = col & 63;
        *(uint2*)&Cb[(((size_t)bidx * 16 + hh) * 64 + j) * T_ + t0] = *(uint2*)p4;
      }
  } else {
#pragma unroll
    for (int mi = 0; mi < 4; ++mi)
#pragma unroll
      for (int ni = 0; ni < FN; ++ni)
#pragma unroll
        for (int r = 0; r < 4; ++r) {
          const int row = crow0 + mi * 16 + r;
          const int col = ccol0 + ni * 16;
          float v = acc[mi][ni][r] * scale;
          if (EPI != 3) v += bias[col];
          if (EPI == 1) v = gelu_f(v);
          const size_t off = (size_t)row * ldc + col;
          if (EPI == 2) v += r1[off];
          if (EPI == 4) v += r1[off] + r2[off];
          if (WF32) Cf[off] = v;
          if (W16) Cb[off] = FP16 ? f2h(v) : f2b(v);
        }
  }
}

// ---------------- fused QKV: one N=3072 GEMM over contiguous WqT|WkT|WvT ----
__global__ __launch_bounds__(256) void gemm_qkv(
    const unsigned short* __restrict__ A, const unsigned short* __restrict__ Wt,
    const float* __restrict__ bq, const float* __restrict__ bk,
    const float* __restrict__ bv, const float* __restrict__ sp,
    const float* __restrict__ ed, unsigned short* __restrict__ q_h,
    unsigned short* __restrict__ kb_h, unsigned short* __restrict__ vt) {
  constexpr int BM = 128, BN = 128, BK = 64, K = 1024;
  __shared__ __align__(16) unsigned short As[BM * BK];
  __shared__ __align__(16) unsigned short Bs[BN * BK];
  const int tid = threadIdx.x;
  const int l = tid & 63, w = tid >> 6;
  const int wm = w >> 1, wn = w & 1;
  const int lr = l & 15, lk = l >> 4;
  const unsigned short* Ab = A + (size_t)blockIdx.y * BM * D_;
  const unsigned short* Bb = Wt + (size_t)blockIdx.x * BN * D_;
  const int ar = tid >> 3, ac = tid & 7;
  const int aswz = ((ac ^ (ar & 7)) << 3);

  f32x4 acc[4][4] = {};
  for (int k0 = 0; k0 < K; k0 += BK) {
#pragma unroll
    for (int i = 0; i < 4; ++i) {
      gload16(Ab + (size_t)(ar + 32 * i) * D_ + k0 + aswz, &As[(size_t)(i * 256 + tid) * 8]);
      gload16(Bb + (size_t)(ar + 32 * i) * D_ + k0 + aswz, &Bs[(size_t)(i * 256 + tid) * 8]);
    }
    __syncthreads();
    bf16x8 af[4][2], bfr[4][2];
#pragma unroll
    for (int mi = 0; mi < 4; ++mi) {
      const int row = wm * 64 + mi * 16 + lr;
#pragma unroll
      for (int kk = 0; kk < 2; ++kk)
        af[mi][kk] = *(const bf16x8*)&As[row * BK + (((kk * 4 + lk) ^ (row & 7)) << 3)];
    }
#pragma unroll
    for (int ni = 0; ni < 4; ++ni) {
      const int row = wn * 64 + ni * 16 + lr;
#pragma unroll
      for (int kk = 0; kk < 2; ++kk)
        bfr[ni][kk] = *(const bf16x8*)&Bs[row * BK + (((kk * 4 + lk) ^ (row & 7)) << 3)];
    }
#pragma unroll
    for (int kk = 0; kk < 2; ++kk)
#pragma unroll
      for (int mi = 0; mi < 4; ++mi)
#pragma unroll
        for (int ni = 0; ni < 4; ++ni)
          acc[mi][ni] = __builtin_amdgcn_mfma_f32_16x16x32_bf16(
              af[mi][kk], bfr[ni][kk], acc[mi][ni], 0, 0, 0);
    __syncthreads();
  }

  const int seg = blockIdx.x >> 3;  // 0=Q, 1=K, 2=V
  const float* bias = seg == 0 ? bq : seg == 1 ? bk : bv;
  const int crow0 = blockIdx.y * BM + wm * 64 + lk * 4;
  const int ccol0 = blockIdx.x * BN + wn * 64 + lr;
  if (seg == 2) {
#pragma unroll
    for (int mi = 0; mi < 4; ++mi)
#pragma unroll
      for (int ni = 0; ni < 4; ++ni) {
        const int row0 = crow0 + mi * 16;
        const int col = (ccol0 + ni * 16) & 1023;
        unsigned short __attribute__((aligned(8))) p4[4];
#pragma unroll
        for (int r = 0; r < 4; ++r) p4[r] = f2h(acc[mi][ni][r] + bias[col]);
        const int bidx = row0 >> 10, t0 = row0 & 1023;
        const int hh = col >> 6, j = col & 63;
        *(uint2*)&vt[(((size_t)bidx * 16 + hh) * 64 + j) * T_ + t0] = *(uint2*)p4;
      }
  } else {
    unsigned short* out = seg == 0 ? q_h : kb_h;
#pragma unroll
    for (int mi = 0; mi < 4; ++mi)
#pragma unroll
      for (int ni = 0; ni < 4; ++ni)
#pragma unroll
        for (int r = 0; r < 4; ++r) {
          const int row = crow0 + mi * 16 + r;
          const int col = (ccol0 + ni * 16) & 1023;
          float v = acc[mi][ni][r] + bias[col];
          const size_t off = (size_t)row * D_ + col;
          if (seg == 1) v += sp[off] + ed[off];
          out[off] = f2h(v);
        }
  }
}

extern "C" void kernel_launch(void* const* d_in, const int* in_sizes, int n_in,
                              void* d_out, int out_size, void* d_ws, size_t ws_size,
                              hipStream_t stream) {
  const float* x    = (const float*)d_in[0];
  const float* sp   = (const float*)d_in[1];
  const float* ed   = (const float*)d_in[2];
  const float* ln1g = (const float*)d_in[3];
  const float* ln1b = (const float*)d_in[4];
  const float* Wq   = (const float*)d_in[5];
  const float* bq   = (const float*)d_in[6];
  const float* Wk   = (const float*)d_in[7];
  const float* bk   = (const float*)d_in[8];
  const float* Wv   = (const float*)d_in[9];
  const float* bvv  = (const float*)d_in[10];
  const float* Wo   = (const float*)d_in[11];
  const float* bo   = (const float*)d_in[12];
  const float* ln2g = (const float*)d_in[13];
  const float* ln2b = (const float*)d_in[14];
  const float* W1   = (const float*)d_in[15];
  const float* b1   = (const float*)d_in[16];
  const float* W2   = (const float*)d_in[17];
  const float* b2   = (const float*)d_in[18];
  const float* lnbg = (const float*)d_in[19];
  const float* lnbb = (const float*)d_in[20];

  float* out_x = (float*)d_out;
  float* attn  = out_x + BTD;
  float* tt    = out_x;

  const size_t MB = 1 << 20;
  char* wsb = (char*)d_ws;
  float*          xn    = (float*)(wsb);                    // [0,16)
  unsigned short* xn_b  = (unsigned short*)(wsb + 16 * MB); // [16,24)
  unsigned short* WqT   = (unsigned short*)(wsb + 24 * MB); // [24,30) Wq|Wk|Wv
  unsigned short* WkT   = (unsigned short*)(wsb + 26 * MB);
  unsigned short* WvT   = (unsigned short*)(wsb + 28 * MB);
  unsigned short* WoT   = (unsigned short*)(wsb + 30 * MB);
  unsigned short* W1T   = (unsigned short*)(wsb + 32 * MB); // [32,40)
  unsigned short* W2T   = (unsigned short*)(wsb + 40 * MB); // [40,48)
  unsigned short* q_h   = (unsigned short*)(wsb + 48 * MB); // [48,56)
  unsigned short* kb_h  = (unsigned short*)(wsb + 56 * MB); // [56,64)
  unsigned short* vt    = (unsigned short*)(wsb + 80 * MB); // [80,88)
  unsigned short* ctx_b = xn_b;                             // [16,24)
  unsigned short* h1_b  = (unsigned short*)(wsb + 48 * MB); // [48,80)
  float*          h2    = (float*)(wsb + 80 * MB);          // [80,96)
  float*          y     = xn;
  unsigned short* y_b   = xn_b;

  dim3 blk(256);
  dim3 blk512(512);
  dim3 g_dd(8, 32);

  // 1. LN1 -> xn (fp32 residual) + xn_b (bf16 GEMM operand)
  ln_rows<<<BT_, blk, 0, stream>>>(x, nullptr, ln1g, ln1b, xn, xn_b);
  // 2. weight transpose+cast
  tcast4<<<dim3(32, 32, 4), blk, 0, stream>>>(Wq, Wk, Wv, Wo, WqT, WkT, WvT, WoT);
  tcast_t<<<dim3(128, 32), blk, 0, stream>>>(W1, W1T, 1024, 4096);
  tcast_t<<<dim3(32, 128), blk, 0, stream>>>(W2, W2T, 4096, 1024);
  // 3. fused QKV (768 blocks): Q->f16, K(+sp+ed)->f16, V->f16 transposed
  gemm_qkv<<<dim3(24, 32), blk, 0, stream>>>(
      xn_b, WqT, bq, bk, bvv, sp, ed, q_h, kb_h, vt);
  // 4. fused scores + softmax + ctx (1024 blocks, 4/CU, race-fixed schedule)
  attn_fused<<<dim3(64, 16), blk, 0, stream>>>(q_h, kb_h, vt, attn, ctx_b);
  // 5. tt = ctx @ Wo + bo + xn (MFMA, 512-thread 8-wave counted-vmcnt pipeline)
  gemm_nt<128, 2, true, false, false, true, 512><<<g_dd, blk512, 0, stream>>>(
      ctx_b, D_, WoT, D_, tt, nullptr, D_, bo, xn, nullptr, 1.f, D_);
  // 6. y = LN2(tt)
  ln_rows<<<BT_, blk, 0, stream>>>(tt, nullptr, ln2g, ln2b, y, y_b);
  // 7. h1 = gelu(y @ W1 + b1) -> bf16 (MFMA, 1024 blocks single-buffer)
  gemm_nt<128, 1, false, true><<<dim3(32, 32), blk, 0, stream>>>(
      y_b, D_, W1T, D_, nullptr, h1_b, F_, b1, nullptr, nullptr, 1.f, D_);
  // 8. h2 = y + (h1 @ W2 + b2)  (MFMA, 512-thread 8-wave counted-vmcnt pipeline)
  gemm_nt<128, 2, true, false, false, true, 512><<<g_dd, blk512, 0, stream>>>(
      h1_b, F_, W2T, F_, h2, nullptr, D_, b2, y, nullptr, 1.f, F_);
  // 9. out = LN(h2)
  ln_rows<<<BT_, blk, 0, stream>>>(h2, nullptr, lnbg, lnbb, out_x, nullptr);
}